// Round 4
// baseline (180.673 us; speedup 1.0000x reference)
//
#include <hip/hip_runtime.h>
#include <math.h>

// ---------------------------------------------------------------------------
// QINRLayer: Linear+BN -> 10-qubit QNN (statevector sim) -> classical branch
// TWO launches:
//   k_pre : BN partial stats, 320 blocks (40 features x 8 sample-slices)
//   k_qnn : partial-reduce + xq recompute (4 samples/block) + gates + QNN
//           + fused epilogue
//
// R14 (this round): FORCE the 64-VGPR occupancy step. R13 diet helped time
// (125->86us profiled) but allocator stayed at 68 VGPR -> still 4 waves/SIMD
// (occupancy 28%, VALUBusy 64% = latency-bound). gfx950 waves/SIMD steps at
// VGPR {64,128,256}; 68 is 4 regs over the 2x-occupancy boundary. This round:
// __attribute__((amdgpu_waves_per_eu(8))) on k_qnn ONLY (source otherwise
// identical to R13) -> compiler budget 512/8 = 64 VGPR. NOTE: deliberately
// re-testing the R2/R3 "spill cascade" knob — that warning was recorded at
// much higher natural pressure; at 68->64 the allocator only needs to
// rematerialize ~4 values. Success gate: VGPR=64, occupancy up, dur down.
// Revert immediately if dur regresses (spill in hot loop).
//
// One wave per sample; 1024 complex amps in registers, PACKED as float2:
//   pair p holds j=2p (.x) and j=2p+1 (.y);  k = lane*16 + j.
//   wire w (0=MSB) <-> lane bit (5-w) for w<6; wires 6,7,8 <-> pair bits 2,1,0;
//   wire 9 <-> intra-pair half.
// Pipe balance (R7: all-DS bound; R9: all-VALU 80% bound; optimum between):
//   xor1/2 quad_perm DPP (1 VALU); xor4/8/16 ds_swizzle (1 DS);
//   xor32 ds_bpermute (1 DS, addr hoisted). Ring gray-perm on ds_bpermute.
//   Measurement phase: xor16/32 on permlane*_swap (2 VALU, low latency).
//
// Circuit algebra (all exact):
//   U0|0..0> product state; ring #1 is a GF(2)-linear basis permutation of a
//   product state -> FUSED into init. F_k = U_{k+1} * E fused layers; 3 rings
//   remain. outs[1]=<X>, outs[2]=outs[3]=-<Y> direct from psi0 (H*H=I, rz3
//   diagonal).
//
// HARD-WON: R8: no same-address atomics across 1024 blocks. R10: no grid-40
// kernels. R11: no grid==CU-count kernels (placement stragglers), no 2
// samples/wave. ~73us of total is fixed harness/graph overhead.
// ---------------------------------------------------------------------------

typedef float v2f __attribute__((ext_vector_type(2)));
typedef unsigned uiv2 __attribute__((ext_vector_type(2)));

__device__ __forceinline__ float bperm1(int addr, float v){
  return __int_as_float(__builtin_amdgcn_ds_bpermute(addr, __float_as_int(v)));
}
__device__ __forceinline__ v2f bperm2(int addr, v2f v){
  v2f r; r.x = bperm1(addr, v.x); r.y = bperm1(addr, v.y); return r;
}
__device__ __forceinline__ v2f vs(float x){ return (v2f){x,x}; }

// ---- cross-lane helpers -----------------------------------------------------
template<int C>
__device__ __forceinline__ float dppf(float x){
  return __int_as_float(__builtin_amdgcn_update_dpp(0, __float_as_int(x),
                                                    C, 0xf, 0xf, true));
}
#define QP_X1 0xB1   // quad_perm [1,0,3,2]  == xor 1
#define QP_X2 0x4E   // quad_perm [2,3,0,1]  == xor 2

// aux arg: ignored by DPP/swizzle variants; bperm byte-addr for xor32f.
__device__ __forceinline__ float xor1f(float x, int /*aux*/){ return dppf<QP_X1>(x); }
__device__ __forceinline__ float xor2f(float x, int /*aux*/){ return dppf<QP_X2>(x); }

// xor4/8/16 on the DS pipe: ds_swizzle BitMode (xor<<10)|0x1F, within 32-lane
// groups (masks 4,8,16 never cross the group boundary).
__device__ __forceinline__ float xor4f(float x, int /*aux*/){
  return __int_as_float(__builtin_amdgcn_ds_swizzle(__float_as_int(x), 0x101F));
}
__device__ __forceinline__ float xor8f(float x, int /*aux*/){
  return __int_as_float(__builtin_amdgcn_ds_swizzle(__float_as_int(x), 0x201F));
}
__device__ __forceinline__ float xor16f(float x, int /*aux*/){
  return __int_as_float(__builtin_amdgcn_ds_swizzle(__float_as_int(x), 0x401F));
}
// xor32 crosses the 32-lane swizzle group: ds_bpermute with hoisted addr.
__device__ __forceinline__ float xor32f(float x, int a32){
  return bperm1(a32, x);
}

// measurement-phase low-latency variants (VALU permlane; aux = lane)
#if __has_builtin(__builtin_amdgcn_permlane16_swap) && __has_builtin(__builtin_amdgcn_permlane32_swap)
__device__ __forceinline__ float xor16p(float x, int lane){
  uiv2 r = __builtin_amdgcn_permlane16_swap(__float_as_uint(x), __float_as_uint(x),
                                            false, false);
  return __uint_as_float((lane & 16) ? r.x : r.y);
}
__device__ __forceinline__ float xor32p(float x, int lane){
  uiv2 r = __builtin_amdgcn_permlane32_swap(__float_as_uint(x), __float_as_uint(x),
                                            false, false);
  return __uint_as_float((lane & 32) ? r.x : r.y);
}
#else
__device__ __forceinline__ float xor16p(float x, int lane){ return bperm1((lane^16)<<2, x); }
__device__ __forceinline__ float xor32p(float x, int lane){ return bperm1((lane^32)<<2, x); }
#endif

#define DEF_XORV(NAME, F1) \
__device__ __forceinline__ v2f NAME(v2f v, int aux){ \
  v2f r; r.x = F1(v.x,aux); r.y = F1(v.y,aux); return r; }
DEF_XORV(xor1v,   xor1f)
DEF_XORV(xor2v,   xor2f)
DEF_XORV(xor4v,   xor4f)
DEF_XORV(xor8v,   xor8f)
DEF_XORV(xor16v,  xor16f)
DEF_XORV(xor32v,  xor32f)
DEF_XORV(xor16pv, xor16p)
DEF_XORV(xor32pv, xor32p)

// full wave64 sum; valid in lane 63 only
__device__ __forceinline__ float dsum(float x){
  x += dppf<0x111>(x);   // row_shr:1
  x += dppf<0x112>(x);   // row_shr:2
  x += dppf<0x114>(x);   // row_shr:4
  x += dppf<0x118>(x);   // row_shr:8
  x += dppf<0x142>(x);   // row_bcast:15
  x += dppf<0x143>(x);   // row_bcast:31
  return x;
}

// ---------------- gate primitives (packed state) ----------------------------

#define DEF_GCROSS(NAME, PFN) \
__device__ __forceinline__ void NAME(v2f (&R)[8], v2f (&I)[8], int aux, bool hi, \
                                     const float* g){ \
  const float gar = hi ? g[6] : g[0], gai = hi ? g[7] : g[1]; \
  const float gbr = hi ? g[4] : g[2], gbi = hi ? g[5] : g[3]; \
  const v2f A=vs(gar), B=vs(gai), C=vs(gbr), D=vs(gbi); \
  _Pragma("unroll") \
  for (int p=0;p<8;++p){ \
    v2f PR = PFN(R[p],aux); \
    v2f PI = PFN(I[p],aux); \
    v2f nr = A*R[p] - B*I[p] + C*PR - D*PI; \
    v2f ni = A*I[p] + B*R[p] + C*PI + D*PR; \
    R[p]=nr; I[p]=ni; } \
}
DEF_GCROSS(g_cross_x32, xor32v)
DEF_GCROSS(g_cross_x16, xor16v)
DEF_GCROSS(g_cross_x8,  xor8v)
DEF_GCROSS(g_cross_x4,  xor4v)
DEF_GCROSS(g_cross_x2,  xor2v)
DEF_GCROSS(g_cross_x1,  xor1v)

// local wires 6,7,8 -> pair masks 4,2,1
template<int PM>
__device__ __forceinline__ void g_localp(v2f (&R)[8], v2f (&I)[8], const float* g)
{
  const v2f g00r=vs(g[0]), g00i=vs(g[1]), g01r=vs(g[2]), g01i=vs(g[3]);
  const v2f g10r=vs(g[4]), g10i=vs(g[5]), g11r=vs(g[6]), g11i=vs(g[7]);
#pragma unroll
  for (int p=0;p<8;++p) if (!(p&PM)) {
    const int q = p|PM;
    v2f r0=R[p], i0=I[p], r1=R[q], i1=I[q];
    R[p] = g00r*r0 - g00i*i0 + g01r*r1 - g01i*i1;
    I[p] = g00r*i0 + g00i*r0 + g01r*i1 + g01i*r1;
    R[q] = g10r*r0 - g10i*i0 + g11r*r1 - g11i*i1;
    I[q] = g10r*i0 + g10i*r0 + g11r*i1 + g11i*r1;
  }
}

// wire 9: intra-pair
__device__ __forceinline__ void g_local9(v2f (&R)[8], v2f (&I)[8], const float* g)
{
  const v2f Gr0 = (v2f){g[0], g[4]};
  const v2f Gi0 = (v2f){g[1], g[5]};
  const v2f Gr1 = (v2f){g[2], g[6]};
  const v2f Gi1 = (v2f){g[3], g[7]};
#pragma unroll
  for (int p=0;p<8;++p) {
    v2f Rx = vs(R[p].x), Ix = vs(I[p].x);
    v2f Ry = vs(R[p].y), Iy = vs(I[p].y);
    R[p] = Gr0*Rx - Gi0*Ix + Gr1*Ry - Gi1*Iy;
    I[p] = Gr0*Ix + Gi0*Rx + Gr1*Iy + Gi1*Ry;
  }
}

// ---------------- CNOT ring --------------------------------------------------
__device__ __forceinline__ void cnot_ring(v2f (&R)[8], v2f (&I)[8],
                                          int addrg, int a32, bool c5)
{
#pragma unroll
  for (int p=0;p<8;++p) R[p] = bperm2(addrg, R[p]);
#pragma unroll
  for (int p=0;p<8;++p) I[p] = bperm2(addrg, I[p]);
#pragma unroll
  for (int p=0;p<4;++p) {
    v2f a=R[p], b=R[p|4];
    R[p]   = c5 ? b : a;
    R[p|4] = c5 ? a : b;
    v2f ai=I[p], bi=I[p|4];
    I[p]   = c5 ? bi : ai;
    I[p|4] = c5 ? ai : bi;
  }
#pragma unroll
  for (int p=0;p<8;++p) if ((p&4)&&!(p&2)) {
    const int q=p|2;
    v2f t=R[p]; R[p]=R[q]; R[q]=t;
    t=I[p]; I[p]=I[q]; I[q]=t;
  }
#pragma unroll
  for (int p=0;p<8;++p) if ((p&2)&&!(p&1)) {
    const int q=p|1;
    v2f t=R[p]; R[p]=R[q]; R[q]=t;
    t=I[p]; I[p]=I[q]; I[q]=t;
  }
#pragma unroll
  for (int p=1;p<8;p+=2) {
    R[p] = __builtin_shufflevector(R[p],R[p],1,0);
    I[p] = __builtin_shufflevector(I[p],I[p],1,0);
  }
#pragma unroll
  for (int p=0;p<8;++p) {
    R[p].y = xor32f(R[p].y, a32);
    I[p].y = xor32f(I[p].y, a32);
  }
}

// ---------------- k_pre: BN partial stats (320 blocks) ----------------------
__global__ __launch_bounds__(256) void k_pre(const float* __restrict__ x,
    const float* __restrict__ qw, const float* __restrict__ qb,
    float* __restrict__ ps)
{
  const int f = blockIdx.x >> 3, slice = blockIdx.x & 7;
  const int t = threadIdx.x;
  __shared__ float wf[40];
  __shared__ float a1[4], a2[4];
  if (t < 40) wf[t] = qw[f*40 + t];
  __syncthreads();
  const float bf = qb[f];
  float s1 = 0.f, s2 = 0.f;
#pragma unroll
  for (int i = 0; i < 4; ++i) {
    const int s = slice*1024 + t + i*256;
    const float4* xr = (const float4*)(x + s*40);
    float d = bf;
#pragma unroll
    for (int q = 0; q < 10; ++q) {
      float4 v = xr[q];
      d = fmaf(v.x, wf[4*q+0], d);
      d = fmaf(v.y, wf[4*q+1], d);
      d = fmaf(v.z, wf[4*q+2], d);
      d = fmaf(v.w, wf[4*q+3], d);
    }
    s1 += d; s2 = fmaf(d, d, s2);
  }
  s1 = dsum(s1); s2 = dsum(s2);
  const int lane = t & 63, wid = t >> 6;
  if (lane == 63) { a1[wid] = s1; a2[wid] = s2; }
  __syncthreads();
  if (t == 0) {
    ps[blockIdx.x*2+0] = a1[0]+a1[1]+a1[2]+a1[3];
    ps[blockIdx.x*2+1] = a2[0]+a2[1]+a2[2]+a2[3];
  }
}

// ---------------- k_qnn: everything else ------------------------------------

#define GEN10(PTR) \
  g_cross_x32(R,I,a32,h0,(PTR)+0);  g_cross_x16(R,I,0,h1,(PTR)+8);  \
  g_cross_x8 (R,I,0,h2,(PTR)+16);   g_cross_x4 (R,I,0,h3,(PTR)+24); \
  g_cross_x2 (R,I,0,h4,(PTR)+32);   g_cross_x1 (R,I,0,h5,(PTR)+40); \
  g_localp<4>(R,I,(PTR)+48);   g_localp<2>(R,I,(PTR)+56);   \
  g_localp<1>(R,I,(PTR)+64);   g_local9(R,I,(PTR)+72);

// R14: force the 64-VGPR budget (8 waves/EU). Plain launch_bounds otherwise.
__global__ __launch_bounds__(256)
__attribute__((amdgpu_waves_per_eu(8)))
void k_qnn(const float* __restrict__ x,
    const float* __restrict__ qlin_w, const float* __restrict__ qlin_b,
    const float* __restrict__ ps,
    const float* __restrict__ gamma, const float* __restrict__ beta,
    const float* __restrict__ rz1, const float* __restrict__ ry1,
    const float* __restrict__ rz2,
    const float* __restrict__ clin_w, const float* __restrict__ clin_b,
    const float* __restrict__ lin_w, const float* __restrict__ lin_b,
    float* __restrict__ out)
{
  const int tix  = threadIdx.x;
  const int lane = tix & 63;
  const int wv   = tix >> 6;

  __shared__ float Gbuf[40][8];     // fused param gates Rz2*Ry1*Rz1
  __shared__ float bnA[40], bnC[40];
  __shared__ float Ebuf[4][10][8];
  __shared__ float Fbuf[4][3][10][8];
  __shared__ float xs [4][40];
  __shared__ float xqs[4][40];
  __shared__ float x1s[4][40];
  __shared__ float x2s[4][40];

  // ---- stage x rows + gate consts + BN reduce, one barrier group
  if (tix < 160) xs[tix/40][tix%40] = x[blockIdx.x*160 + tix];
  if (tix >= 160 && tix < 200) {
    const int gi = tix - 160;
    float g = rz1[gi], ay = ry1[gi], bz = rz2[gi];
    float ha = 0.5f*ay, hp = 0.5f*(bz+g), hm = 0.5f*(bz-g);
    float ca = __cosf(ha), sa = __sinf(ha);
    float cp = __cosf(hp), sp = __sinf(hp);
    float cm = __cosf(hm), sm = __sinf(hm);
    float* G = &Gbuf[gi][0];
    G[0]= ca*cp; G[1]=-ca*sp;
    G[2]=-sa*cm; G[3]= sa*sm;
    G[4]= sa*cm; G[5]= sa*sm;
    G[6]= ca*cp; G[7]= ca*sp;
  }
  if (tix >= 200 && tix < 240) {
    const int f = tix - 200;
    float s1 = 0.f, s2 = 0.f;
#pragma unroll
    for (int k = 0; k < 8; ++k) {
      s1 += ps[(f*8+k)*2+0];
      s2 += ps[(f*8+k)*2+1];
    }
    float mu  = s1 * (1.f/8192.f);
    float var = s2 * (1.f/8192.f) - mu*mu;
    float a = gamma[f] * rsqrtf(var + 1e-5f);
    bnA[f] = a; bnC[f] = beta[f] - mu*a;
  }
  __syncthreads();

  // ---- xq for our 4 samples (weights L2-hot, aligned float4 rows)
  if (tix < 160) {
    const int sl = tix/40, f = tix - sl*40;
    const float4* qw = (const float4*)(qlin_w + f*40);
    float acc = qlin_b[f];
#pragma unroll
    for (int q = 0; q < 10; ++q) {
      float4 v = qw[q];
      acc = fmaf(v.x, xs[sl][4*q+0], acc);
      acc = fmaf(v.y, xs[sl][4*q+1], acc);
      acc = fmaf(v.z, xs[sl][4*q+2], acc);
      acc = fmaf(v.w, xs[sl][4*q+3], acc);
    }
    xqs[sl][f] = acc;
  }
  __syncthreads();

  // ---- per-sample fused encoder matrix per wire: Rx(f3) Rz(f2) Ry(f1) Rx(f0)
  if (lane < 10) {
    const int i = lane;
    const int f = 4*i;
    float a0 = 0.5f * fmaf(xqs[wv][f+0], bnA[f+0], bnC[f+0]);
    float a1 = 0.5f * fmaf(xqs[wv][f+1], bnA[f+1], bnC[f+1]);
    float a2 = 0.5f * fmaf(xqs[wv][f+2], bnA[f+2], bnC[f+2]);
    float a3 = 0.5f * fmaf(xqs[wv][f+3], bnA[f+3], bnC[f+3]);
    float c0 = __cosf(a0), s0 = __sinf(a0);
    float c1 = __cosf(a1), s1 = __sinf(a1);
    float c2 = __cosf(a2), s2 = __sinf(a2);
    float c3 = __cosf(a3), s3 = __sinf(a3);
    float A00r=c1*c0, A00i= s1*s0;
    float A01r=-s1*c0, A01i=-c1*s0;
    float A10r= s1*c0, A10i=-c1*s0;
    float A11r= c1*c0, A11i=-s1*s0;
    float B00r = A00r*c2 + A00i*s2, B00i = A00i*c2 - A00r*s2;
    float B01r = A01r*c2 + A01i*s2, B01i = A01i*c2 - A01r*s2;
    float B10r = A10r*c2 - A10i*s2, B10i = A10i*c2 + A10r*s2;
    float B11r = A11r*c2 - A11i*s2, B11i = A11i*c2 + A11r*s2;
    float* e = &Ebuf[wv][i][0];
    e[0] = c3*B00r + s3*B10i;  e[1] = c3*B00i - s3*B10r;
    e[2] = c3*B01r + s3*B11i;  e[3] = c3*B01i - s3*B11r;
    e[4] = c3*B10r + s3*B00i;  e[5] = c3*B10i - s3*B00r;
    e[6] = c3*B11r + s3*B01i;  e[7] = c3*B11i - s3*B01r;
  }

  // ---- fused F_k = U_{k+1} * E (same wave reads its own Ebuf rows)
  if (lane < 30) {
    const int k = lane/10, i = lane - k*10;
    const float* U = &Gbuf[(k+1)*10 + i][0];
    const float* E = &Ebuf[wv][i][0];
    float u00r=U[0],u00i=U[1],u01r=U[2],u01i=U[3],u10r=U[4],u10i=U[5],u11r=U[6],u11i=U[7];
    float e00r=E[0],e00i=E[1],e01r=E[2],e01i=E[3],e10r=E[4],e10i=E[5],e11r=E[6],e11i=E[7];
    float* F = &Fbuf[wv][k][i][0];
    F[0] = u00r*e00r - u00i*e00i + u01r*e10r - u01i*e10i;
    F[1] = u00r*e00i + u00i*e00r + u01r*e10i + u01i*e10r;
    F[2] = u00r*e01r - u00i*e01i + u01r*e11r - u01i*e11i;
    F[3] = u00r*e01i + u00i*e01r + u01r*e11i + u01i*e11r;
    F[4] = u10r*e00r - u10i*e00i + u11r*e10r - u11i*e10i;
    F[5] = u10r*e00i + u10i*e00r + u11r*e10i + u11i*e10r;
    F[6] = u10r*e01r - u10i*e01i + u11r*e11r - u11i*e11i;
    F[7] = u10r*e01i + u10i*e01r + u11r*e11i + u11i*e11r;
  }

  const bool h0 = (lane & 32) != 0;
  const bool h1 = (lane & 16) != 0;
  const bool h2 = (lane &  8) != 0;
  const bool h3 = (lane &  4) != 0;
  const bool h4 = (lane &  2) != 0;
  const bool h5 = (lane &  1) != 0;
  const int addrg = (lane ^ (lane >> 1)) << 2;
  const int a32   = (lane ^ 32) << 2;

  // ---- init: state = ring( U0 |0..0> ) — ring #1 fused analytically.
  //  amp(L,j) = c(L0) * phi6[b3']phi7[b2'] * phi8[b1']phi9[b0'], where
  //  L0 = gray(L) ^ 48*(j&1);  j' bits: b3'=b3^(L&1), b2'=b2^b3, b1'=b1^b2,
  //  b0'=b0^b1.  (verified vs sequential-CNOT gather; see header)
  //  Folded form (R11-verified): ce/co * p67 recomputed per p.
  v2f R[8], I[8];
  {
    const int l0=lane&1, l1=(lane>>1)&1, l2=(lane>>2)&1,
              l3=(lane>>3)&1, l4=(lane>>4)&1, l5=(lane>>5)&1;
    // cs = phi2[l3^l4] phi3[l2^l3] phi4[l1^l2] phi5[l0^l1]
    float csr, csi;
    {
      int b = l3^l4; csr = Gbuf[2][4*b]; csi = Gbuf[2][4*b+1];
      b = l2^l3; float gr=Gbuf[3][4*b], gi=Gbuf[3][4*b+1];
      float tr = csr*gr - csi*gi, ti = csr*gi + csi*gr; csr=tr; csi=ti;
      b = l1^l2; gr=Gbuf[4][4*b]; gi=Gbuf[4][4*b+1];
      tr = csr*gr - csi*gi; ti = csr*gi + csi*gr; csr=tr; csi=ti;
      b = l0^l1; gr=Gbuf[5][4*b]; gi=Gbuf[5][4*b+1];
      tr = csr*gr - csi*gi; ti = csr*gi + csi*gr; csr=tr; csi=ti;
    }
    // ce = phi0[l5] phi1[l4^l5] cs ; co = phi0[1^l5] phi1[1^(l4^l5)] cs
    float cer,cei,cor_,coi;
    {
      const int b5 = l5, b4 = l4^l5;
      float ar = Gbuf[0][4*b5],     ai = Gbuf[0][4*b5+1];
      float br = Gbuf[1][4*b4],     bi = Gbuf[1][4*b4+1];
      float tr = ar*br - ai*bi,     ti = ar*bi + ai*br;
      cer = tr*csr - ti*csi;  cei = tr*csi + ti*csr;
      ar = Gbuf[0][4*(1^b5)]; ai = Gbuf[0][4*(1^b5)+1];
      br = Gbuf[1][4*(1^b4)]; bi = Gbuf[1][4*(1^b4)+1];
      tr = ar*br - ai*bi;     ti = ar*bi + ai*br;
      cor_ = tr*csr - ti*csi; coi = tr*csi + ti*csr;
    }
    // local pair products
    float p67r[4], p67i[4], p89r[4], p89i[4];
#pragma unroll
    for (int b6=0;b6<2;++b6)
#pragma unroll
      for (int b7=0;b7<2;++b7) {
        const float x6r = Gbuf[6][4*b6], x6i = Gbuf[6][4*b6+1];
        const float x7r = Gbuf[7][4*b7], x7i = Gbuf[7][4*b7+1];
        p67r[b6*2+b7] = x6r*x7r - x6i*x7i;
        p67i[b6*2+b7] = x6r*x7i + x6i*x7r;
      }
#pragma unroll
    for (int b8=0;b8<2;++b8)
#pragma unroll
      for (int b9=0;b9<2;++b9) {
        const float x8r = Gbuf[8][4*b8], x8i = Gbuf[8][4*b8+1];
        const float x9r = Gbuf[9][4*b9], x9i = Gbuf[9][4*b9+1];
        p89r[b8*2+b9] = x8r*x9r - x8i*x9i;
        p89i[b8*2+b9] = x8r*x9i + x8i*x9r;
      }
    // folded: t = (ce|co)*p67 recomputed per p (4 transients vs 16-reg arrays)
#pragma unroll
    for (int p=0;p<8;++p) {
      const int b3 = (p>>2)&1, b2 = (p>>1)&1, b1 = p&1;
      const int i67 = ((b3 ^ l0) << 1) | (b2 ^ b3);
      const int b1p = b1 ^ b2;
      const int ix  = (b1p<<1) | b1;
      const int iy  = (b1p<<1) | (1^b1);
      const float ter  = cer*p67r[i67] - cei*p67i[i67];
      const float tei  = cer*p67i[i67] + cei*p67r[i67];
      const float tor_ = cor_*p67r[i67] - coi*p67i[i67];
      const float toi  = cor_*p67i[i67] + coi*p67r[i67];
      R[p].x = ter*p89r[ix] - tei*p89i[ix];
      I[p].x = ter*p89i[ix] + tei*p89r[ix];
      R[p].y = tor_*p89r[iy] - toi*p89i[iy];
      I[p].y = tor_*p89i[iy] + toi*p89r[iy];
    }
  }

  // ---- main circuit: 3 fused layers with 3 remaining rings
  { const float* F = &Fbuf[wv][0][0][0]; GEN10(F) }
  cnot_ring(R,I,addrg,a32,h5);
  { const float* F = &Fbuf[wv][1][0][0]; GEN10(F) }
  cnot_ring(R,I,addrg,a32,h5);
  { const float* F = &Fbuf[wv][2][0][0]; GEN10(F) }
  cnot_ring(R,I,addrg,a32,h5);

  float* dst = &x1s[wv][0];

  // ---- outs[0]: <Z_w> from probabilities (streamed — no pv[8] array)
  {
    v2f T8 = vs(0.f);
    v2f aa[4];
#pragma unroll
    for (int m=0;m<4;++m) aa[m] = vs(0.f);
#pragma unroll
    for (int p=0;p<8;++p) {
      v2f t = R[p]*R[p] + I[p]*I[p];
      T8 = (p&1) ? (T8 - t) : (T8 + t);
      aa[p>>1] += t;
    }
    v2f T7 = (aa[0]-aa[1]) + (aa[2]-aa[3]);
    v2f T6 = (aa[0]+aa[1]) - (aa[2]+aa[3]);
    v2f S  = (aa[0]+aa[1]) + (aa[2]+aa[3]);
    float q8 = T8.x + T8.y;
    float q7 = T7.x + T7.y;
    float q6 = T6.x + T6.y;
    float q9 = S.x - S.y;
    float P  = S.x + S.y;

    float v = P;
    { float pt = xor1f (v,0);    v = h5 ? (pt - v) : (pt + v); }
    { float pt = xor2f (v,0);    v = h4 ? (pt - v) : (pt + v); }
    { float pt = xor4f (v,0);    v = h3 ? (pt - v) : (pt + v); }
    { float pt = xor8f (v,0);    v = h2 ? (pt - v) : (pt + v); }
    { float pt = xor16p(v,lane); v = h1 ? (pt - v) : (pt + v); }
    { float pt = xor32p(v,lane); v = h0 ? (pt - v) : (pt + v); }

    q6 = dsum(q6); q7 = dsum(q7); q8 = dsum(q8); q9 = dsum(q9);

    if (lane==32) dst[0]=v;
    if (lane==16) dst[1]=v;
    if (lane== 8) dst[2]=v;
    if (lane== 4) dst[3]=v;
    if (lane== 2) dst[4]=v;
    if (lane== 1) dst[5]=v;
    if (lane==63){ dst[6]=q6; dst[7]=q7; dst[8]=q8; dst[9]=q9; }
  }

  // ---- outs[1]=<X>, outs[2]=outs[3]=-<Y>, direct from psi0
  //      (cross-wire pairs on low-latency permlane/DPP/swizzle variants)
#define XYC(PFN,AUX,HW,W) { \
    v2f U=vs(0.f), V=vs(0.f); \
    _Pragma("unroll") \
    for (int p=0;p<8;++p) { \
      v2f PR = PFN(R[p],AUX); \
      v2f PI = PFN(I[p],AUX); \
      U += R[p]*PR + I[p]*PI; \
      V += I[p]*PR - R[p]*PI; \
    } \
    float u = U.x + U.y; \
    float vv = V.x + V.y; \
    vv = (HW) ? vv : -vv; \
    u = dsum(u); vv = dsum(vv); \
    if (lane==63){ dst[10+(W)]=u; dst[20+(W)]=vv; dst[30+(W)]=vv; } \
  }
  XYC(xor32pv,lane,h0,0) XYC(xor16pv,lane,h1,1) XYC(xor8v,0,h2,2)
  XYC(xor4v ,0,h3,3) XYC(xor2v ,0,h4,4) XYC(xor1v,0,h5,5)
#undef XYC

#define XYL(PM,W) { \
    v2f U=vs(0.f), V=vs(0.f); \
    _Pragma("unroll") \
    for (int p=0;p<8;++p) if (!(p&(PM))) { \
      const int q=p|(PM); \
      U += R[p]*R[q] + I[p]*I[q]; \
      V += I[p]*R[q] - R[p]*I[q]; \
    } \
    float u = U.x + U.y; \
    float vv = V.x + V.y; \
    u = dsum(u); vv = dsum(vv); \
    if (lane==63){ dst[10+(W)]=2.f*u; float y=-2.f*vv; dst[20+(W)]=y; dst[30+(W)]=y; } \
  }
  XYL(4,6) XYL(2,7) XYL(1,8)
#undef XYL

  {
    float u=0.f, vv=0.f;
#pragma unroll
    for (int p=0;p<8;++p) {
      u  = fmaf(R[p].x, R[p].y, u);  u  = fmaf(I[p].x, I[p].y, u);
      vv = fmaf(I[p].x, R[p].y, vv); vv = fmaf(-R[p].x, I[p].y, vv);
    }
    u = dsum(u); vv = dsum(vv);
    if (lane==63){ dst[19]=2.f*u; float y=-2.f*vv; dst[29]=y; dst[39]=y; }
  }

  // ---- fused epilogue: x2 = relu(x@clin^T+b); out = [x1,x2]@lin^T + b
  __syncthreads();
  if (tix < 160) {
    const int sl = tix/40, f = tix - sl*40;
    const float4* cw = (const float4*)(clin_w + f*40);
    float acc = clin_b[f];
#pragma unroll
    for (int q = 0; q < 10; ++q) {
      float4 v = cw[q];
      acc = fmaf(v.x, xs[sl][4*q+0], acc);
      acc = fmaf(v.y, xs[sl][4*q+1], acc);
      acc = fmaf(v.z, xs[sl][4*q+2], acc);
      acc = fmaf(v.w, xs[sl][4*q+3], acc);
    }
    x2s[sl][f] = fmaxf(acc, 0.f);
  }
  __syncthreads();
  if (tix < 160) {
    const int sl = tix/40, f = tix - sl*40;
    const float4* lw = (const float4*)(lin_w + f*80);
    float o = lin_b[f];
#pragma unroll
    for (int q = 0; q < 10; ++q) {
      float4 v = lw[q];
      o = fmaf(v.x, x1s[sl][4*q+0], o);
      o = fmaf(v.y, x1s[sl][4*q+1], o);
      o = fmaf(v.z, x1s[sl][4*q+2], o);
      o = fmaf(v.w, x1s[sl][4*q+3], o);
    }
#pragma unroll
    for (int q = 10; q < 20; ++q) {
      float4 v = lw[q];
      o = fmaf(v.x, x2s[sl][4*(q-10)+0], o);
      o = fmaf(v.y, x2s[sl][4*(q-10)+1], o);
      o = fmaf(v.z, x2s[sl][4*(q-10)+2], o);
      o = fmaf(v.w, x2s[sl][4*(q-10)+3], o);
    }
    out[blockIdx.x*160 + tix] = o;
  }
}

// ---------------- launch ---------------------------------------------------
extern "C" void kernel_launch(void* const* d_in, const int* in_sizes, int n_in,
                              void* d_out, int out_size, void* d_ws, size_t ws_size,
                              hipStream_t stream)
{
  const float* x      = (const float*)d_in[0];
  const float* qlin_w = (const float*)d_in[1];
  const float* qlin_b = (const float*)d_in[2];
  const float* bn_g   = (const float*)d_in[3];
  const float* bn_b   = (const float*)d_in[4];
  const float* clin_w = (const float*)d_in[5];
  const float* clin_b = (const float*)d_in[6];
  const float* lin_w  = (const float*)d_in[7];
  const float* lin_b  = (const float*)d_in[8];
  const float* rz1    = (const float*)d_in[9];
  const float* ry1    = (const float*)d_in[10];
  const float* rz2    = (const float*)d_in[11];

  float* ps  = (float*)d_ws;     // 640 floats of partials
  float* out = (float*)d_out;

  hipLaunchKernelGGL(k_pre, dim3(320),  dim3(256), 0, stream, x, qlin_w, qlin_b, ps);
  hipLaunchKernelGGL(k_qnn, dim3(2048), dim3(256), 0, stream,
                     x, qlin_w, qlin_b, ps, bn_g, bn_b, rz1, ry1, rz2,
                     clin_w, clin_b, lin_w, lin_b, out);
}

// Round 5
// 161.022 us; speedup vs baseline: 1.1220x; 1.1220x over previous
//
#include <hip/hip_runtime.h>
#include <math.h>

// ---------------------------------------------------------------------------
// QINRLayer: Linear+BN -> 10-qubit QNN (statevector sim) -> classical branch
// TWO launches:
//   k_pre : BN partial stats, 320 blocks (40 features x 8 sample-slices)
//   k_qnn : partial-reduce + xq recompute (4 samples/block) + gates + QNN
//           + fused epilogue
//
// R15 (this round): NATURAL register diet via in-flight window chunking.
// R14 post-mortem: amdgpu_waves_per_eu(8) forced VGPR to 32 -> spill cascade
// (hbm_bytes 2.4MB -> 245MB, dur 86->97+us). Forcing is DEAD (R2/R3
// confirmed quantitatively). But occupancy DID respond (28->64%), so the
// 64-VGPR step model holds. This round: cap the peak live set at source
// level — the 8-pair unrolled g_cross/XYC loops hold 32 in-flight permute
// result regs (8 pairs x PR,PI v2f); chunk into 2x4 pairs with
// __builtin_amdgcn_sched_barrier(0) between halves -> peak in-flight 16.
// NO forcing attribute. Success gate: VGPR_Count <= 64 naturally.
//
// One wave per sample; 1024 complex amps in registers, PACKED as float2:
//   pair p holds j=2p (.x) and j=2p+1 (.y);  k = lane*16 + j.
//   wire w (0=MSB) <-> lane bit (5-w) for w<6; wires 6,7,8 <-> pair bits 2,1,0;
//   wire 9 <-> intra-pair half.
// Pipe balance (R7: all-DS bound; R9: all-VALU 80% bound; optimum between):
//   xor1/2 quad_perm DPP (1 VALU); xor4/8/16 ds_swizzle (1 DS);
//   xor32 ds_bpermute (1 DS, addr hoisted). Ring gray-perm on ds_bpermute.
//   Measurement phase: xor16/32 on permlane*_swap (2 VALU, low latency).
//
// Circuit algebra (all exact):
//   U0|0..0> product state; ring #1 is a GF(2)-linear basis permutation of a
//   product state -> FUSED into init. F_k = U_{k+1} * E fused layers; 3 rings
//   remain. outs[1]=<X>, outs[2]=outs[3]=-<Y> direct from psi0 (H*H=I, rz3
//   diagonal).
//
// HARD-WON: do NOT force waves-per-EU (R2/R3, reconfirmed R14: spill cascade,
// 100x memory traffic). R8: no same-address atomics across 1024 blocks.
// R10: no grid-40 kernels. R11: no grid==CU-count kernels, no 2 samples/wave.
// ~73us of total is fixed harness/graph overhead.
// ---------------------------------------------------------------------------

typedef float v2f __attribute__((ext_vector_type(2)));
typedef unsigned uiv2 __attribute__((ext_vector_type(2)));

__device__ __forceinline__ float bperm1(int addr, float v){
  return __int_as_float(__builtin_amdgcn_ds_bpermute(addr, __float_as_int(v)));
}
__device__ __forceinline__ v2f bperm2(int addr, v2f v){
  v2f r; r.x = bperm1(addr, v.x); r.y = bperm1(addr, v.y); return r;
}
__device__ __forceinline__ v2f vs(float x){ return (v2f){x,x}; }

// ---- cross-lane helpers -----------------------------------------------------
template<int C>
__device__ __forceinline__ float dppf(float x){
  return __int_as_float(__builtin_amdgcn_update_dpp(0, __float_as_int(x),
                                                    C, 0xf, 0xf, true));
}
#define QP_X1 0xB1   // quad_perm [1,0,3,2]  == xor 1
#define QP_X2 0x4E   // quad_perm [2,3,0,1]  == xor 2

// aux arg: ignored by DPP/swizzle variants; bperm byte-addr for xor32f.
__device__ __forceinline__ float xor1f(float x, int /*aux*/){ return dppf<QP_X1>(x); }
__device__ __forceinline__ float xor2f(float x, int /*aux*/){ return dppf<QP_X2>(x); }

// xor4/8/16 on the DS pipe: ds_swizzle BitMode (xor<<10)|0x1F, within 32-lane
// groups (masks 4,8,16 never cross the group boundary).
__device__ __forceinline__ float xor4f(float x, int /*aux*/){
  return __int_as_float(__builtin_amdgcn_ds_swizzle(__float_as_int(x), 0x101F));
}
__device__ __forceinline__ float xor8f(float x, int /*aux*/){
  return __int_as_float(__builtin_amdgcn_ds_swizzle(__float_as_int(x), 0x201F));
}
__device__ __forceinline__ float xor16f(float x, int /*aux*/){
  return __int_as_float(__builtin_amdgcn_ds_swizzle(__float_as_int(x), 0x401F));
}
// xor32 crosses the 32-lane swizzle group: ds_bpermute with hoisted addr.
__device__ __forceinline__ float xor32f(float x, int a32){
  return bperm1(a32, x);
}

// measurement-phase low-latency variants (VALU permlane; aux = lane)
#if __has_builtin(__builtin_amdgcn_permlane16_swap) && __has_builtin(__builtin_amdgcn_permlane32_swap)
__device__ __forceinline__ float xor16p(float x, int lane){
  uiv2 r = __builtin_amdgcn_permlane16_swap(__float_as_uint(x), __float_as_uint(x),
                                            false, false);
  return __uint_as_float((lane & 16) ? r.x : r.y);
}
__device__ __forceinline__ float xor32p(float x, int lane){
  uiv2 r = __builtin_amdgcn_permlane32_swap(__float_as_uint(x), __float_as_uint(x),
                                            false, false);
  return __uint_as_float((lane & 32) ? r.x : r.y);
}
#else
__device__ __forceinline__ float xor16p(float x, int lane){ return bperm1((lane^16)<<2, x); }
__device__ __forceinline__ float xor32p(float x, int lane){ return bperm1((lane^32)<<2, x); }
#endif

#define DEF_XORV(NAME, F1) \
__device__ __forceinline__ v2f NAME(v2f v, int aux){ \
  v2f r; r.x = F1(v.x,aux); r.y = F1(v.y,aux); return r; }
DEF_XORV(xor1v,   xor1f)
DEF_XORV(xor2v,   xor2f)
DEF_XORV(xor4v,   xor4f)
DEF_XORV(xor8v,   xor8f)
DEF_XORV(xor16v,  xor16f)
DEF_XORV(xor32v,  xor32f)
DEF_XORV(xor16pv, xor16p)
DEF_XORV(xor32pv, xor32p)

// full wave64 sum; valid in lane 63 only
__device__ __forceinline__ float dsum(float x){
  x += dppf<0x111>(x);   // row_shr:1
  x += dppf<0x112>(x);   // row_shr:2
  x += dppf<0x114>(x);   // row_shr:4
  x += dppf<0x118>(x);   // row_shr:8
  x += dppf<0x142>(x);   // row_bcast:15
  x += dppf<0x143>(x);   // row_bcast:31
  return x;
}

// ---------------- gate primitives (packed state) ----------------------------
// R15: 2x4-pair chunking caps in-flight PR/PI at 16 regs (was 32).

#define DEF_GCROSS(NAME, PFN) \
__device__ __forceinline__ void NAME(v2f (&R)[8], v2f (&I)[8], int aux, bool hi, \
                                     const float* g){ \
  const float gar = hi ? g[6] : g[0], gai = hi ? g[7] : g[1]; \
  const float gbr = hi ? g[4] : g[2], gbi = hi ? g[5] : g[3]; \
  const v2f A=vs(gar), B=vs(gai), C=vs(gbr), D=vs(gbi); \
  _Pragma("unroll") \
  for (int c=0;c<2;++c){ \
    _Pragma("unroll") \
    for (int p=c*4;p<c*4+4;++p){ \
      v2f PR = PFN(R[p],aux); \
      v2f PI = PFN(I[p],aux); \
      v2f nr = A*R[p] - B*I[p] + C*PR - D*PI; \
      v2f ni = A*I[p] + B*R[p] + C*PI + D*PR; \
      R[p]=nr; I[p]=ni; } \
    if (c==0) __builtin_amdgcn_sched_barrier(0); \
  } \
}
DEF_GCROSS(g_cross_x32, xor32v)
DEF_GCROSS(g_cross_x16, xor16v)
DEF_GCROSS(g_cross_x8,  xor8v)
DEF_GCROSS(g_cross_x4,  xor4v)
DEF_GCROSS(g_cross_x2,  xor2v)
DEF_GCROSS(g_cross_x1,  xor1v)

// local wires 6,7,8 -> pair masks 4,2,1
template<int PM>
__device__ __forceinline__ void g_localp(v2f (&R)[8], v2f (&I)[8], const float* g)
{
  const v2f g00r=vs(g[0]), g00i=vs(g[1]), g01r=vs(g[2]), g01i=vs(g[3]);
  const v2f g10r=vs(g[4]), g10i=vs(g[5]), g11r=vs(g[6]), g11i=vs(g[7]);
#pragma unroll
  for (int p=0;p<8;++p) if (!(p&PM)) {
    const int q = p|PM;
    v2f r0=R[p], i0=I[p], r1=R[q], i1=I[q];
    R[p] = g00r*r0 - g00i*i0 + g01r*r1 - g01i*i1;
    I[p] = g00r*i0 + g00i*r0 + g01r*i1 + g01i*r1;
    R[q] = g10r*r0 - g10i*i0 + g11r*r1 - g11i*i1;
    I[q] = g10r*i0 + g10i*r0 + g11r*i1 + g11i*r1;
  }
}

// wire 9: intra-pair
__device__ __forceinline__ void g_local9(v2f (&R)[8], v2f (&I)[8], const float* g)
{
  const v2f Gr0 = (v2f){g[0], g[4]};
  const v2f Gi0 = (v2f){g[1], g[5]};
  const v2f Gr1 = (v2f){g[2], g[6]};
  const v2f Gi1 = (v2f){g[3], g[7]};
#pragma unroll
  for (int p=0;p<8;++p) {
    v2f Rx = vs(R[p].x), Ix = vs(I[p].x);
    v2f Ry = vs(R[p].y), Iy = vs(I[p].y);
    R[p] = Gr0*Rx - Gi0*Ix + Gr1*Ry - Gi1*Iy;
    I[p] = Gr0*Ix + Gi0*Rx + Gr1*Iy + Gi1*Ry;
  }
}

// ---------------- CNOT ring --------------------------------------------------
// bperm2 loops are in-place (no extra in-flight regs) — left unchunked.
__device__ __forceinline__ void cnot_ring(v2f (&R)[8], v2f (&I)[8],
                                          int addrg, int a32, bool c5)
{
#pragma unroll
  for (int p=0;p<8;++p) R[p] = bperm2(addrg, R[p]);
#pragma unroll
  for (int p=0;p<8;++p) I[p] = bperm2(addrg, I[p]);
#pragma unroll
  for (int p=0;p<4;++p) {
    v2f a=R[p], b=R[p|4];
    R[p]   = c5 ? b : a;
    R[p|4] = c5 ? a : b;
    v2f ai=I[p], bi=I[p|4];
    I[p]   = c5 ? bi : ai;
    I[p|4] = c5 ? ai : bi;
  }
#pragma unroll
  for (int p=0;p<8;++p) if ((p&4)&&!(p&2)) {
    const int q=p|2;
    v2f t=R[p]; R[p]=R[q]; R[q]=t;
    t=I[p]; I[p]=I[q]; I[q]=t;
  }
#pragma unroll
  for (int p=0;p<8;++p) if ((p&2)&&!(p&1)) {
    const int q=p|1;
    v2f t=R[p]; R[p]=R[q]; R[q]=t;
    t=I[p]; I[p]=I[q]; I[q]=t;
  }
#pragma unroll
  for (int p=1;p<8;p+=2) {
    R[p] = __builtin_shufflevector(R[p],R[p],1,0);
    I[p] = __builtin_shufflevector(I[p],I[p],1,0);
  }
#pragma unroll
  for (int p=0;p<8;++p) {
    R[p].y = xor32f(R[p].y, a32);
    I[p].y = xor32f(I[p].y, a32);
  }
}

// ---------------- k_pre: BN partial stats (320 blocks) ----------------------
__global__ __launch_bounds__(256) void k_pre(const float* __restrict__ x,
    const float* __restrict__ qw, const float* __restrict__ qb,
    float* __restrict__ ps)
{
  const int f = blockIdx.x >> 3, slice = blockIdx.x & 7;
  const int t = threadIdx.x;
  __shared__ float wf[40];
  __shared__ float a1[4], a2[4];
  if (t < 40) wf[t] = qw[f*40 + t];
  __syncthreads();
  const float bf = qb[f];
  float s1 = 0.f, s2 = 0.f;
#pragma unroll
  for (int i = 0; i < 4; ++i) {
    const int s = slice*1024 + t + i*256;
    const float4* xr = (const float4*)(x + s*40);
    float d = bf;
#pragma unroll
    for (int q = 0; q < 10; ++q) {
      float4 v = xr[q];
      d = fmaf(v.x, wf[4*q+0], d);
      d = fmaf(v.y, wf[4*q+1], d);
      d = fmaf(v.z, wf[4*q+2], d);
      d = fmaf(v.w, wf[4*q+3], d);
    }
    s1 += d; s2 = fmaf(d, d, s2);
  }
  s1 = dsum(s1); s2 = dsum(s2);
  const int lane = t & 63, wid = t >> 6;
  if (lane == 63) { a1[wid] = s1; a2[wid] = s2; }
  __syncthreads();
  if (t == 0) {
    ps[blockIdx.x*2+0] = a1[0]+a1[1]+a1[2]+a1[3];
    ps[blockIdx.x*2+1] = a2[0]+a2[1]+a2[2]+a2[3];
  }
}

// ---------------- k_qnn: everything else ------------------------------------

#define GEN10(PTR) \
  g_cross_x32(R,I,a32,h0,(PTR)+0);  g_cross_x16(R,I,0,h1,(PTR)+8);  \
  g_cross_x8 (R,I,0,h2,(PTR)+16);   g_cross_x4 (R,I,0,h3,(PTR)+24); \
  g_cross_x2 (R,I,0,h4,(PTR)+32);   g_cross_x1 (R,I,0,h5,(PTR)+40); \
  g_localp<4>(R,I,(PTR)+48);   g_localp<2>(R,I,(PTR)+56);   \
  g_localp<1>(R,I,(PTR)+64);   g_local9(R,I,(PTR)+72);

// Plain launch bounds — NO waves_per_eu forcing (R14 spill cascade).
__global__ __launch_bounds__(256) void k_qnn(const float* __restrict__ x,
    const float* __restrict__ qlin_w, const float* __restrict__ qlin_b,
    const float* __restrict__ ps,
    const float* __restrict__ gamma, const float* __restrict__ beta,
    const float* __restrict__ rz1, const float* __restrict__ ry1,
    const float* __restrict__ rz2,
    const float* __restrict__ clin_w, const float* __restrict__ clin_b,
    const float* __restrict__ lin_w, const float* __restrict__ lin_b,
    float* __restrict__ out)
{
  const int tix  = threadIdx.x;
  const int lane = tix & 63;
  const int wv   = tix >> 6;

  __shared__ float Gbuf[40][8];     // fused param gates Rz2*Ry1*Rz1
  __shared__ float bnA[40], bnC[40];
  __shared__ float Ebuf[4][10][8];
  __shared__ float Fbuf[4][3][10][8];
  __shared__ float xs [4][40];
  __shared__ float xqs[4][40];
  __shared__ float x1s[4][40];
  __shared__ float x2s[4][40];

  // ---- stage x rows + gate consts + BN reduce, one barrier group
  if (tix < 160) xs[tix/40][tix%40] = x[blockIdx.x*160 + tix];
  if (tix >= 160 && tix < 200) {
    const int gi = tix - 160;
    float g = rz1[gi], ay = ry1[gi], bz = rz2[gi];
    float ha = 0.5f*ay, hp = 0.5f*(bz+g), hm = 0.5f*(bz-g);
    float ca = __cosf(ha), sa = __sinf(ha);
    float cp = __cosf(hp), sp = __sinf(hp);
    float cm = __cosf(hm), sm = __sinf(hm);
    float* G = &Gbuf[gi][0];
    G[0]= ca*cp; G[1]=-ca*sp;
    G[2]=-sa*cm; G[3]= sa*sm;
    G[4]= sa*cm; G[5]= sa*sm;
    G[6]= ca*cp; G[7]= ca*sp;
  }
  if (tix >= 200 && tix < 240) {
    const int f = tix - 200;
    float s1 = 0.f, s2 = 0.f;
#pragma unroll
    for (int k = 0; k < 8; ++k) {
      s1 += ps[(f*8+k)*2+0];
      s2 += ps[(f*8+k)*2+1];
    }
    float mu  = s1 * (1.f/8192.f);
    float var = s2 * (1.f/8192.f) - mu*mu;
    float a = gamma[f] * rsqrtf(var + 1e-5f);
    bnA[f] = a; bnC[f] = beta[f] - mu*a;
  }
  __syncthreads();

  // ---- xq for our 4 samples (weights L2-hot, aligned float4 rows)
  if (tix < 160) {
    const int sl = tix/40, f = tix - sl*40;
    const float4* qw = (const float4*)(qlin_w + f*40);
    float acc = qlin_b[f];
#pragma unroll
    for (int q = 0; q < 10; ++q) {
      float4 v = qw[q];
      acc = fmaf(v.x, xs[sl][4*q+0], acc);
      acc = fmaf(v.y, xs[sl][4*q+1], acc);
      acc = fmaf(v.z, xs[sl][4*q+2], acc);
      acc = fmaf(v.w, xs[sl][4*q+3], acc);
    }
    xqs[sl][f] = acc;
  }
  __syncthreads();

  // ---- per-sample fused encoder matrix per wire: Rx(f3) Rz(f2) Ry(f1) Rx(f0)
  if (lane < 10) {
    const int i = lane;
    const int f = 4*i;
    float a0 = 0.5f * fmaf(xqs[wv][f+0], bnA[f+0], bnC[f+0]);
    float a1 = 0.5f * fmaf(xqs[wv][f+1], bnA[f+1], bnC[f+1]);
    float a2 = 0.5f * fmaf(xqs[wv][f+2], bnA[f+2], bnC[f+2]);
    float a3 = 0.5f * fmaf(xqs[wv][f+3], bnA[f+3], bnC[f+3]);
    float c0 = __cosf(a0), s0 = __sinf(a0);
    float c1 = __cosf(a1), s1 = __sinf(a1);
    float c2 = __cosf(a2), s2 = __sinf(a2);
    float c3 = __cosf(a3), s3 = __sinf(a3);
    float A00r=c1*c0, A00i= s1*s0;
    float A01r=-s1*c0, A01i=-c1*s0;
    float A10r= s1*c0, A10i=-c1*s0;
    float A11r= c1*c0, A11i=-s1*s0;
    float B00r = A00r*c2 + A00i*s2, B00i = A00i*c2 - A00r*s2;
    float B01r = A01r*c2 + A01i*s2, B01i = A01i*c2 - A01r*s2;
    float B10r = A10r*c2 - A10i*s2, B10i = A10i*c2 + A10r*s2;
    float B11r = A11r*c2 - A11i*s2, B11i = A11i*c2 + A11r*s2;
    float* e = &Ebuf[wv][i][0];
    e[0] = c3*B00r + s3*B10i;  e[1] = c3*B00i - s3*B10r;
    e[2] = c3*B01r + s3*B11i;  e[3] = c3*B01i - s3*B11r;
    e[4] = c3*B10r + s3*B00i;  e[5] = c3*B10i - s3*B00r;
    e[6] = c3*B11r + s3*B01i;  e[7] = c3*B11i - s3*B01r;
  }

  // ---- fused F_k = U_{k+1} * E (same wave reads its own Ebuf rows)
  if (lane < 30) {
    const int k = lane/10, i = lane - k*10;
    const float* U = &Gbuf[(k+1)*10 + i][0];
    const float* E = &Ebuf[wv][i][0];
    float u00r=U[0],u00i=U[1],u01r=U[2],u01i=U[3],u10r=U[4],u10i=U[5],u11r=U[6],u11i=U[7];
    float e00r=E[0],e00i=E[1],e01r=E[2],e01i=E[3],e10r=E[4],e10i=E[5],e11r=E[6],e11i=E[7];
    float* F = &Fbuf[wv][k][i][0];
    F[0] = u00r*e00r - u00i*e00i + u01r*e10r - u01i*e10i;
    F[1] = u00r*e00i + u00i*e00r + u01r*e10i + u01i*e10r;
    F[2] = u00r*e01r - u00i*e01i + u01r*e11r - u01i*e11i;
    F[3] = u00r*e01i + u00i*e01r + u01r*e11i + u01i*e11r;
    F[4] = u10r*e00r - u10i*e00i + u11r*e10r - u11i*e10i;
    F[5] = u10r*e00i + u10i*e00r + u11r*e10i + u11i*e10r;
    F[6] = u10r*e01r - u10i*e01i + u11r*e11r - u11i*e11i;
    F[7] = u10r*e01i + u10i*e01r + u11r*e11i + u11i*e11r;
  }

  const bool h0 = (lane & 32) != 0;
  const bool h1 = (lane & 16) != 0;
  const bool h2 = (lane &  8) != 0;
  const bool h3 = (lane &  4) != 0;
  const bool h4 = (lane &  2) != 0;
  const bool h5 = (lane &  1) != 0;
  const int addrg = (lane ^ (lane >> 1)) << 2;
  const int a32   = (lane ^ 32) << 2;

  // ---- init: state = ring( U0 |0..0> ) — ring #1 fused analytically.
  //  amp(L,j) = c(L0) * phi6[b3']phi7[b2'] * phi8[b1']phi9[b0'], where
  //  L0 = gray(L) ^ 48*(j&1);  j' bits: b3'=b3^(L&1), b2'=b2^b3, b1'=b1^b2,
  //  b0'=b0^b1.  (verified vs sequential-CNOT gather; see header)
  //  Folded form (R11-verified): ce/co * p67 recomputed per p.
  v2f R[8], I[8];
  {
    const int l0=lane&1, l1=(lane>>1)&1, l2=(lane>>2)&1,
              l3=(lane>>3)&1, l4=(lane>>4)&1, l5=(lane>>5)&1;
    // cs = phi2[l3^l4] phi3[l2^l3] phi4[l1^l2] phi5[l0^l1]
    float csr, csi;
    {
      int b = l3^l4; csr = Gbuf[2][4*b]; csi = Gbuf[2][4*b+1];
      b = l2^l3; float gr=Gbuf[3][4*b], gi=Gbuf[3][4*b+1];
      float tr = csr*gr - csi*gi, ti = csr*gi + csi*gr; csr=tr; csi=ti;
      b = l1^l2; gr=Gbuf[4][4*b]; gi=Gbuf[4][4*b+1];
      tr = csr*gr - csi*gi; ti = csr*gi + csi*gr; csr=tr; csi=ti;
      b = l0^l1; gr=Gbuf[5][4*b]; gi=Gbuf[5][4*b+1];
      tr = csr*gr - csi*gi; ti = csr*gi + csi*gr; csr=tr; csi=ti;
    }
    // ce = phi0[l5] phi1[l4^l5] cs ; co = phi0[1^l5] phi1[1^(l4^l5)] cs
    float cer,cei,cor_,coi;
    {
      const int b5 = l5, b4 = l4^l5;
      float ar = Gbuf[0][4*b5],     ai = Gbuf[0][4*b5+1];
      float br = Gbuf[1][4*b4],     bi = Gbuf[1][4*b4+1];
      float tr = ar*br - ai*bi,     ti = ar*bi + ai*br;
      cer = tr*csr - ti*csi;  cei = tr*csi + ti*csr;
      ar = Gbuf[0][4*(1^b5)]; ai = Gbuf[0][4*(1^b5)+1];
      br = Gbuf[1][4*(1^b4)]; bi = Gbuf[1][4*(1^b4)+1];
      tr = ar*br - ai*bi;     ti = ar*bi + ai*br;
      cor_ = tr*csr - ti*csi; coi = tr*csi + ti*csr;
    }
    // local pair products
    float p67r[4], p67i[4], p89r[4], p89i[4];
#pragma unroll
    for (int b6=0;b6<2;++b6)
#pragma unroll
      for (int b7=0;b7<2;++b7) {
        const float x6r = Gbuf[6][4*b6], x6i = Gbuf[6][4*b6+1];
        const float x7r = Gbuf[7][4*b7], x7i = Gbuf[7][4*b7+1];
        p67r[b6*2+b7] = x6r*x7r - x6i*x7i;
        p67i[b6*2+b7] = x6r*x7i + x6i*x7r;
      }
#pragma unroll
    for (int b8=0;b8<2;++b8)
#pragma unroll
      for (int b9=0;b9<2;++b9) {
        const float x8r = Gbuf[8][4*b8], x8i = Gbuf[8][4*b8+1];
        const float x9r = Gbuf[9][4*b9], x9i = Gbuf[9][4*b9+1];
        p89r[b8*2+b9] = x8r*x9r - x8i*x9i;
        p89i[b8*2+b9] = x8r*x9i + x8i*x9r;
      }
    // folded: t = (ce|co)*p67 recomputed per p (4 transients vs 16-reg arrays)
#pragma unroll
    for (int p=0;p<8;++p) {
      const int b3 = (p>>2)&1, b2 = (p>>1)&1, b1 = p&1;
      const int i67 = ((b3 ^ l0) << 1) | (b2 ^ b3);
      const int b1p = b1 ^ b2;
      const int ix  = (b1p<<1) | b1;
      const int iy  = (b1p<<1) | (1^b1);
      const float ter  = cer*p67r[i67] - cei*p67i[i67];
      const float tei  = cer*p67i[i67] + cei*p67r[i67];
      const float tor_ = cor_*p67r[i67] - coi*p67i[i67];
      const float toi  = cor_*p67i[i67] + coi*p67r[i67];
      R[p].x = ter*p89r[ix] - tei*p89i[ix];
      I[p].x = ter*p89i[ix] + tei*p89r[ix];
      R[p].y = tor_*p89r[iy] - toi*p89i[iy];
      I[p].y = tor_*p89i[iy] + toi*p89r[iy];
    }
  }

  // ---- main circuit: 3 fused layers with 3 remaining rings
  { const float* F = &Fbuf[wv][0][0][0]; GEN10(F) }
  cnot_ring(R,I,addrg,a32,h5);
  { const float* F = &Fbuf[wv][1][0][0]; GEN10(F) }
  cnot_ring(R,I,addrg,a32,h5);
  { const float* F = &Fbuf[wv][2][0][0]; GEN10(F) }
  cnot_ring(R,I,addrg,a32,h5);

  float* dst = &x1s[wv][0];

  // ---- outs[0]: <Z_w> from probabilities (streamed — no pv[8] array)
  {
    v2f T8 = vs(0.f);
    v2f aa[4];
#pragma unroll
    for (int m=0;m<4;++m) aa[m] = vs(0.f);
#pragma unroll
    for (int p=0;p<8;++p) {
      v2f t = R[p]*R[p] + I[p]*I[p];
      T8 = (p&1) ? (T8 - t) : (T8 + t);
      aa[p>>1] += t;
    }
    v2f T7 = (aa[0]-aa[1]) + (aa[2]-aa[3]);
    v2f T6 = (aa[0]+aa[1]) - (aa[2]+aa[3]);
    v2f S  = (aa[0]+aa[1]) + (aa[2]+aa[3]);
    float q8 = T8.x + T8.y;
    float q7 = T7.x + T7.y;
    float q6 = T6.x + T6.y;
    float q9 = S.x - S.y;
    float P  = S.x + S.y;

    float v = P;
    { float pt = xor1f (v,0);    v = h5 ? (pt - v) : (pt + v); }
    { float pt = xor2f (v,0);    v = h4 ? (pt - v) : (pt + v); }
    { float pt = xor4f (v,0);    v = h3 ? (pt - v) : (pt + v); }
    { float pt = xor8f (v,0);    v = h2 ? (pt - v) : (pt + v); }
    { float pt = xor16p(v,lane); v = h1 ? (pt - v) : (pt + v); }
    { float pt = xor32p(v,lane); v = h0 ? (pt - v) : (pt + v); }

    q6 = dsum(q6); q7 = dsum(q7); q8 = dsum(q8); q9 = dsum(q9);

    if (lane==32) dst[0]=v;
    if (lane==16) dst[1]=v;
    if (lane== 8) dst[2]=v;
    if (lane== 4) dst[3]=v;
    if (lane== 2) dst[4]=v;
    if (lane== 1) dst[5]=v;
    if (lane==63){ dst[6]=q6; dst[7]=q7; dst[8]=q8; dst[9]=q9; }
  }

  // ---- outs[1]=<X>, outs[2]=outs[3]=-<Y>, direct from psi0
  //      (chunked 2x4 pairs, same in-flight cap as gates)
#define XYC(PFN,AUX,HW,W) { \
    v2f U=vs(0.f), V=vs(0.f); \
    _Pragma("unroll") \
    for (int c=0;c<2;++c){ \
      _Pragma("unroll") \
      for (int p=c*4;p<c*4+4;++p) { \
        v2f PR = PFN(R[p],AUX); \
        v2f PI = PFN(I[p],AUX); \
        U += R[p]*PR + I[p]*PI; \
        V += I[p]*PR - R[p]*PI; \
      } \
      if (c==0) __builtin_amdgcn_sched_barrier(0); \
    } \
    float u = U.x + U.y; \
    float vv = V.x + V.y; \
    vv = (HW) ? vv : -vv; \
    u = dsum(u); vv = dsum(vv); \
    if (lane==63){ dst[10+(W)]=u; dst[20+(W)]=vv; dst[30+(W)]=vv; } \
  }
  XYC(xor32pv,lane,h0,0) XYC(xor16pv,lane,h1,1) XYC(xor8v,0,h2,2)
  XYC(xor4v ,0,h3,3) XYC(xor2v ,0,h4,4) XYC(xor1v,0,h5,5)
#undef XYC

#define XYL(PM,W) { \
    v2f U=vs(0.f), V=vs(0.f); \
    _Pragma("unroll") \
    for (int p=0;p<8;++p) if (!(p&(PM))) { \
      const int q=p|(PM); \
      U += R[p]*R[q] + I[p]*I[q]; \
      V += I[p]*R[q] - R[p]*I[q]; \
    } \
    float u = U.x + U.y; \
    float vv = V.x + V.y; \
    u = dsum(u); vv = dsum(vv); \
    if (lane==63){ dst[10+(W)]=2.f*u; float y=-2.f*vv; dst[20+(W)]=y; dst[30+(W)]=y; } \
  }
  XYL(4,6) XYL(2,7) XYL(1,8)
#undef XYL

  {
    float u=0.f, vv=0.f;
#pragma unroll
    for (int p=0;p<8;++p) {
      u  = fmaf(R[p].x, R[p].y, u);  u  = fmaf(I[p].x, I[p].y, u);
      vv = fmaf(I[p].x, R[p].y, vv); vv = fmaf(-R[p].x, I[p].y, vv);
    }
    u = dsum(u); vv = dsum(vv);
    if (lane==63){ dst[19]=2.f*u; float y=-2.f*vv; dst[29]=y; dst[39]=y; }
  }

  // ---- fused epilogue: x2 = relu(x@clin^T+b); out = [x1,x2]@lin^T + b
  __syncthreads();
  if (tix < 160) {
    const int sl = tix/40, f = tix - sl*40;
    const float4* cw = (const float4*)(clin_w + f*40);
    float acc = clin_b[f];
#pragma unroll
    for (int q = 0; q < 10; ++q) {
      float4 v = cw[q];
      acc = fmaf(v.x, xs[sl][4*q+0], acc);
      acc = fmaf(v.y, xs[sl][4*q+1], acc);
      acc = fmaf(v.z, xs[sl][4*q+2], acc);
      acc = fmaf(v.w, xs[sl][4*q+3], acc);
    }
    x2s[sl][f] = fmaxf(acc, 0.f);
  }
  __syncthreads();
  if (tix < 160) {
    const int sl = tix/40, f = tix - sl*40;
    const float4* lw = (const float4*)(lin_w + f*80);
    float o = lin_b[f];
#pragma unroll
    for (int q = 0; q < 10; ++q) {
      float4 v = lw[q];
      o = fmaf(v.x, x1s[sl][4*q+0], o);
      o = fmaf(v.y, x1s[sl][4*q+1], o);
      o = fmaf(v.z, x1s[sl][4*q+2], o);
      o = fmaf(v.w, x1s[sl][4*q+3], o);
    }
#pragma unroll
    for (int q = 10; q < 20; ++q) {
      float4 v = lw[q];
      o = fmaf(v.x, x2s[sl][4*(q-10)+0], o);
      o = fmaf(v.y, x2s[sl][4*(q-10)+1], o);
      o = fmaf(v.z, x2s[sl][4*(q-10)+2], o);
      o = fmaf(v.w, x2s[sl][4*(q-10)+3], o);
    }
    out[blockIdx.x*160 + tix] = o;
  }
}

// ---------------- launch ---------------------------------------------------
extern "C" void kernel_launch(void* const* d_in, const int* in_sizes, int n_in,
                              void* d_out, int out_size, void* d_ws, size_t ws_size,
                              hipStream_t stream)
{
  const float* x      = (const float*)d_in[0];
  const float* qlin_w = (const float*)d_in[1];
  const float* qlin_b = (const float*)d_in[2];
  const float* bn_g   = (const float*)d_in[3];
  const float* bn_b   = (const float*)d_in[4];
  const float* clin_w = (const float*)d_in[5];
  const float* clin_b = (const float*)d_in[6];
  const float* lin_w  = (const float*)d_in[7];
  const float* lin_b  = (const float*)d_in[8];
  const float* rz1    = (const float*)d_in[9];
  const float* ry1    = (const float*)d_in[10];
  const float* rz2    = (const float*)d_in[11];

  float* ps  = (float*)d_ws;     // 640 floats of partials
  float* out = (float*)d_out;

  hipLaunchKernelGGL(k_pre, dim3(320),  dim3(256), 0, stream, x, qlin_w, qlin_b, ps);
  hipLaunchKernelGGL(k_qnn, dim3(2048), dim3(256), 0, stream,
                     x, qlin_w, qlin_b, ps, bn_g, bn_b, rz1, ry1, rz2,
                     clin_w, clin_b, lin_w, lin_b, out);
}

// Round 6
// 159.557 us; speedup vs baseline: 1.1323x; 1.0092x over previous
//
#include <hip/hip_runtime.h>
#include <math.h>

// ---------------------------------------------------------------------------
// QINRLayer: Linear+BN -> 10-qubit QNN (statevector sim) -> classical branch
// TWO launches:
//   k_pre : BN partial stats, 320 blocks (40 features x 8 sample-slices)
//   k_qnn : partial-reduce + xq recompute (4 samples/block) + gates + QNN
//           + fused epilogue
//
// R16 (this round): DS->VALU REBALANCE on top of R15's occupancy platform.
// R15 post-mortem: chunking got VGPR 68->48, occupancy 28->43%, e2e FLAT ->
// occupancy wasn't binding; kernel sits at VALU~45%/DS~50us equilibrium
// (pipes alternate on the critical path). VALU now has ~35pts headroom
// (was 79% in R10 when R12 pushed work TO the DS pipe — tradeoff inverted).
// Changes: (a) gate-phase xor16 -> permlane16_swap (VALU, -96 DS/wave);
// (b) ring-tail xor32 (.y half-swap) -> permlane32_swap (-48 DS/wave).
// Total -144 DS ops/wave (~20% of DS), +288 VALU (within R9's 80% ceiling).
// Gray gather + xor4/8 stay DS (general perm / no VALU equivalent).
// Keep R15 chunking (it bought the occupancy making this shift pay).
//
// One wave per sample; 1024 complex amps in registers, PACKED as float2:
//   pair p holds j=2p (.x) and j=2p+1 (.y);  k = lane*16 + j.
//   wire w (0=MSB) <-> lane bit (5-w) for w<6; wires 6,7,8 <-> pair bits 2,1,0;
//   wire 9 <-> intra-pair half.
// Pipe split (R16): xor1/2 DPP; xor16/32-swap permlane (VALU);
//   xor4/8 ds_swizzle; ring gray-gather ds_bpermute (DS).
//
// Circuit algebra (all exact):
//   U0|0..0> product state; ring #1 is a GF(2)-linear basis permutation of a
//   product state -> FUSED into init. F_k = U_{k+1} * E fused layers; 3 rings
//   remain. outs[1]=<X>, outs[2]=outs[3]=-<Y> direct from psi0 (H*H=I, rz3
//   diagonal).
//
// HARD-WON: do NOT force waves-per-EU (R2/R3, reconfirmed R14: spill cascade,
// 100x memory traffic). R8: no same-address atomics across 1024 blocks.
// R10: no grid-40 kernels. R11: no grid==CU-count kernels, no 2 samples/wave.
// ~73us of total is fixed harness/graph overhead. Profiled-under-rocprof
// dispatch times are NOT comparable across rounds; trust harness e2e.
// ---------------------------------------------------------------------------

typedef float v2f __attribute__((ext_vector_type(2)));
typedef unsigned uiv2 __attribute__((ext_vector_type(2)));

__device__ __forceinline__ float bperm1(int addr, float v){
  return __int_as_float(__builtin_amdgcn_ds_bpermute(addr, __float_as_int(v)));
}
__device__ __forceinline__ v2f bperm2(int addr, v2f v){
  v2f r; r.x = bperm1(addr, v.x); r.y = bperm1(addr, v.y); return r;
}
__device__ __forceinline__ v2f vs(float x){ return (v2f){x,x}; }

// ---- cross-lane helpers -----------------------------------------------------
template<int C>
__device__ __forceinline__ float dppf(float x){
  return __int_as_float(__builtin_amdgcn_update_dpp(0, __float_as_int(x),
                                                    C, 0xf, 0xf, true));
}
#define QP_X1 0xB1   // quad_perm [1,0,3,2]  == xor 1
#define QP_X2 0x4E   // quad_perm [2,3,0,1]  == xor 2

// aux arg: ignored by DPP/swizzle variants; lane for permlane variants.
__device__ __forceinline__ float xor1f(float x, int /*aux*/){ return dppf<QP_X1>(x); }
__device__ __forceinline__ float xor2f(float x, int /*aux*/){ return dppf<QP_X2>(x); }

// xor4/8 on the DS pipe: ds_swizzle BitMode (xor<<10)|0x1F, within 32-lane
// groups (masks 4,8 never cross the group boundary).
__device__ __forceinline__ float xor4f(float x, int /*aux*/){
  return __int_as_float(__builtin_amdgcn_ds_swizzle(__float_as_int(x), 0x101F));
}
__device__ __forceinline__ float xor8f(float x, int /*aux*/){
  return __int_as_float(__builtin_amdgcn_ds_swizzle(__float_as_int(x), 0x201F));
}

// xor16/32 on VALU permlane swaps (2 VALU each, low latency) — R16 rebalance.
#if __has_builtin(__builtin_amdgcn_permlane16_swap) && __has_builtin(__builtin_amdgcn_permlane32_swap)
__device__ __forceinline__ float xor16p(float x, int lane){
  uiv2 r = __builtin_amdgcn_permlane16_swap(__float_as_uint(x), __float_as_uint(x),
                                            false, false);
  return __uint_as_float((lane & 16) ? r.x : r.y);
}
__device__ __forceinline__ float xor32p(float x, int lane){
  uiv2 r = __builtin_amdgcn_permlane32_swap(__float_as_uint(x), __float_as_uint(x),
                                            false, false);
  return __uint_as_float((lane & 32) ? r.x : r.y);
}
#else
__device__ __forceinline__ float xor16p(float x, int lane){ return bperm1((lane^16)<<2, x); }
__device__ __forceinline__ float xor32p(float x, int lane){ return bperm1((lane^32)<<2, x); }
#endif

// DS fallback for xor32 where we still want it on the DS pipe (gate x32):
__device__ __forceinline__ float xor32f(float x, int a32){
  return bperm1(a32, x);
}

#define DEF_XORV(NAME, F1) \
__device__ __forceinline__ v2f NAME(v2f v, int aux){ \
  v2f r; r.x = F1(v.x,aux); r.y = F1(v.y,aux); return r; }
DEF_XORV(xor1v,   xor1f)
DEF_XORV(xor2v,   xor2f)
DEF_XORV(xor4v,   xor4f)
DEF_XORV(xor8v,   xor8f)
DEF_XORV(xor16pv, xor16p)
DEF_XORV(xor32pv, xor32p)
DEF_XORV(xor32v,  xor32f)

// full wave64 sum; valid in lane 63 only
__device__ __forceinline__ float dsum(float x){
  x += dppf<0x111>(x);   // row_shr:1
  x += dppf<0x112>(x);   // row_shr:2
  x += dppf<0x114>(x);   // row_shr:4
  x += dppf<0x118>(x);   // row_shr:8
  x += dppf<0x142>(x);   // row_bcast:15
  x += dppf<0x143>(x);   // row_bcast:31
  return x;
}

// ---------------- gate primitives (packed state) ----------------------------
// 2x4-pair chunking caps in-flight PR/PI at 16 regs (R15, kept).

#define DEF_GCROSS(NAME, PFN) \
__device__ __forceinline__ void NAME(v2f (&R)[8], v2f (&I)[8], int aux, bool hi, \
                                     const float* g){ \
  const float gar = hi ? g[6] : g[0], gai = hi ? g[7] : g[1]; \
  const float gbr = hi ? g[4] : g[2], gbi = hi ? g[5] : g[3]; \
  const v2f A=vs(gar), B=vs(gai), C=vs(gbr), D=vs(gbi); \
  _Pragma("unroll") \
  for (int c=0;c<2;++c){ \
    _Pragma("unroll") \
    for (int p=c*4;p<c*4+4;++p){ \
      v2f PR = PFN(R[p],aux); \
      v2f PI = PFN(I[p],aux); \
      v2f nr = A*R[p] - B*I[p] + C*PR - D*PI; \
      v2f ni = A*I[p] + B*R[p] + C*PI + D*PR; \
      R[p]=nr; I[p]=ni; } \
    if (c==0) __builtin_amdgcn_sched_barrier(0); \
  } \
}
DEF_GCROSS(g_cross_x32, xor32v)    // DS (bperm, hoisted addr)
DEF_GCROSS(g_cross_x16, xor16pv)   // VALU permlane (R16)
DEF_GCROSS(g_cross_x8,  xor8v)     // DS swizzle
DEF_GCROSS(g_cross_x4,  xor4v)     // DS swizzle
DEF_GCROSS(g_cross_x2,  xor2v)     // DPP
DEF_GCROSS(g_cross_x1,  xor1v)     // DPP

// local wires 6,7,8 -> pair masks 4,2,1
template<int PM>
__device__ __forceinline__ void g_localp(v2f (&R)[8], v2f (&I)[8], const float* g)
{
  const v2f g00r=vs(g[0]), g00i=vs(g[1]), g01r=vs(g[2]), g01i=vs(g[3]);
  const v2f g10r=vs(g[4]), g10i=vs(g[5]), g11r=vs(g[6]), g11i=vs(g[7]);
#pragma unroll
  for (int p=0;p<8;++p) if (!(p&PM)) {
    const int q = p|PM;
    v2f r0=R[p], i0=I[p], r1=R[q], i1=I[q];
    R[p] = g00r*r0 - g00i*i0 + g01r*r1 - g01i*i1;
    I[p] = g00r*i0 + g00i*r0 + g01r*i1 + g01i*r1;
    R[q] = g10r*r0 - g10i*i0 + g11r*r1 - g11i*i1;
    I[q] = g10r*i0 + g10i*r0 + g11r*i1 + g11i*r1;
  }
}

// wire 9: intra-pair
__device__ __forceinline__ void g_local9(v2f (&R)[8], v2f (&I)[8], const float* g)
{
  const v2f Gr0 = (v2f){g[0], g[4]};
  const v2f Gi0 = (v2f){g[1], g[5]};
  const v2f Gr1 = (v2f){g[2], g[6]};
  const v2f Gi1 = (v2f){g[3], g[7]};
#pragma unroll
  for (int p=0;p<8;++p) {
    v2f Rx = vs(R[p].x), Ix = vs(I[p].x);
    v2f Ry = vs(R[p].y), Iy = vs(I[p].y);
    R[p] = Gr0*Rx - Gi0*Ix + Gr1*Ry - Gi1*Iy;
    I[p] = Gr0*Ix + Gi0*Rx + Gr1*Iy + Gi1*Ry;
  }
}

// ---------------- CNOT ring --------------------------------------------------
// Gray gather stays DS (general permute); final .y half-swap -> permlane32
// (R16: -16 DS/ring, +32 VALU/ring).
__device__ __forceinline__ void cnot_ring(v2f (&R)[8], v2f (&I)[8],
                                          int addrg, int lane, bool c5)
{
#pragma unroll
  for (int p=0;p<8;++p) R[p] = bperm2(addrg, R[p]);
#pragma unroll
  for (int p=0;p<8;++p) I[p] = bperm2(addrg, I[p]);
#pragma unroll
  for (int p=0;p<4;++p) {
    v2f a=R[p], b=R[p|4];
    R[p]   = c5 ? b : a;
    R[p|4] = c5 ? a : b;
    v2f ai=I[p], bi=I[p|4];
    I[p]   = c5 ? bi : ai;
    I[p|4] = c5 ? ai : bi;
  }
#pragma unroll
  for (int p=0;p<8;++p) if ((p&4)&&!(p&2)) {
    const int q=p|2;
    v2f t=R[p]; R[p]=R[q]; R[q]=t;
    t=I[p]; I[p]=I[q]; I[q]=t;
  }
#pragma unroll
  for (int p=0;p<8;++p) if ((p&2)&&!(p&1)) {
    const int q=p|1;
    v2f t=R[p]; R[p]=R[q]; R[q]=t;
    t=I[p]; I[p]=I[q]; I[q]=t;
  }
#pragma unroll
  for (int p=1;p<8;p+=2) {
    R[p] = __builtin_shufflevector(R[p],R[p],1,0);
    I[p] = __builtin_shufflevector(I[p],I[p],1,0);
  }
#pragma unroll
  for (int p=0;p<8;++p) {
    R[p].y = xor32p(R[p].y, lane);
    I[p].y = xor32p(I[p].y, lane);
  }
}

// ---------------- k_pre: BN partial stats (320 blocks) ----------------------
__global__ __launch_bounds__(256) void k_pre(const float* __restrict__ x,
    const float* __restrict__ qw, const float* __restrict__ qb,
    float* __restrict__ ps)
{
  const int f = blockIdx.x >> 3, slice = blockIdx.x & 7;
  const int t = threadIdx.x;
  __shared__ float wf[40];
  __shared__ float a1[4], a2[4];
  if (t < 40) wf[t] = qw[f*40 + t];
  __syncthreads();
  const float bf = qb[f];
  float s1 = 0.f, s2 = 0.f;
#pragma unroll
  for (int i = 0; i < 4; ++i) {
    const int s = slice*1024 + t + i*256;
    const float4* xr = (const float4*)(x + s*40);
    float d = bf;
#pragma unroll
    for (int q = 0; q < 10; ++q) {
      float4 v = xr[q];
      d = fmaf(v.x, wf[4*q+0], d);
      d = fmaf(v.y, wf[4*q+1], d);
      d = fmaf(v.z, wf[4*q+2], d);
      d = fmaf(v.w, wf[4*q+3], d);
    }
    s1 += d; s2 = fmaf(d, d, s2);
  }
  s1 = dsum(s1); s2 = dsum(s2);
  const int lane = t & 63, wid = t >> 6;
  if (lane == 63) { a1[wid] = s1; a2[wid] = s2; }
  __syncthreads();
  if (t == 0) {
    ps[blockIdx.x*2+0] = a1[0]+a1[1]+a1[2]+a1[3];
    ps[blockIdx.x*2+1] = a2[0]+a2[1]+a2[2]+a2[3];
  }
}

// ---------------- k_qnn: everything else ------------------------------------

#define GEN10(PTR) \
  g_cross_x32(R,I,a32,h0,(PTR)+0);   g_cross_x16(R,I,lane,h1,(PTR)+8);  \
  g_cross_x8 (R,I,0,h2,(PTR)+16);    g_cross_x4 (R,I,0,h3,(PTR)+24); \
  g_cross_x2 (R,I,0,h4,(PTR)+32);    g_cross_x1 (R,I,0,h5,(PTR)+40); \
  g_localp<4>(R,I,(PTR)+48);   g_localp<2>(R,I,(PTR)+56);   \
  g_localp<1>(R,I,(PTR)+64);   g_local9(R,I,(PTR)+72);

// Plain launch bounds — NO waves_per_eu forcing (R14 spill cascade).
__global__ __launch_bounds__(256) void k_qnn(const float* __restrict__ x,
    const float* __restrict__ qlin_w, const float* __restrict__ qlin_b,
    const float* __restrict__ ps,
    const float* __restrict__ gamma, const float* __restrict__ beta,
    const float* __restrict__ rz1, const float* __restrict__ ry1,
    const float* __restrict__ rz2,
    const float* __restrict__ clin_w, const float* __restrict__ clin_b,
    const float* __restrict__ lin_w, const float* __restrict__ lin_b,
    float* __restrict__ out)
{
  const int tix  = threadIdx.x;
  const int lane = tix & 63;
  const int wv   = tix >> 6;

  __shared__ float Gbuf[40][8];     // fused param gates Rz2*Ry1*Rz1
  __shared__ float bnA[40], bnC[40];
  __shared__ float Ebuf[4][10][8];
  __shared__ float Fbuf[4][3][10][8];
  __shared__ float xs [4][40];
  __shared__ float xqs[4][40];
  __shared__ float x1s[4][40];
  __shared__ float x2s[4][40];

  // ---- stage x rows + gate consts + BN reduce, one barrier group
  if (tix < 160) xs[tix/40][tix%40] = x[blockIdx.x*160 + tix];
  if (tix >= 160 && tix < 200) {
    const int gi = tix - 160;
    float g = rz1[gi], ay = ry1[gi], bz = rz2[gi];
    float ha = 0.5f*ay, hp = 0.5f*(bz+g), hm = 0.5f*(bz-g);
    float ca = __cosf(ha), sa = __sinf(ha);
    float cp = __cosf(hp), sp = __sinf(hp);
    float cm = __cosf(hm), sm = __sinf(hm);
    float* G = &Gbuf[gi][0];
    G[0]= ca*cp; G[1]=-ca*sp;
    G[2]=-sa*cm; G[3]= sa*sm;
    G[4]= sa*cm; G[5]= sa*sm;
    G[6]= ca*cp; G[7]= ca*sp;
  }
  if (tix >= 200 && tix < 240) {
    const int f = tix - 200;
    float s1 = 0.f, s2 = 0.f;
#pragma unroll
    for (int k = 0; k < 8; ++k) {
      s1 += ps[(f*8+k)*2+0];
      s2 += ps[(f*8+k)*2+1];
    }
    float mu  = s1 * (1.f/8192.f);
    float var = s2 * (1.f/8192.f) - mu*mu;
    float a = gamma[f] * rsqrtf(var + 1e-5f);
    bnA[f] = a; bnC[f] = beta[f] - mu*a;
  }
  __syncthreads();

  // ---- xq for our 4 samples (weights L2-hot, aligned float4 rows)
  if (tix < 160) {
    const int sl = tix/40, f = tix - sl*40;
    const float4* qw = (const float4*)(qlin_w + f*40);
    float acc = qlin_b[f];
#pragma unroll
    for (int q = 0; q < 10; ++q) {
      float4 v = qw[q];
      acc = fmaf(v.x, xs[sl][4*q+0], acc);
      acc = fmaf(v.y, xs[sl][4*q+1], acc);
      acc = fmaf(v.z, xs[sl][4*q+2], acc);
      acc = fmaf(v.w, xs[sl][4*q+3], acc);
    }
    xqs[sl][f] = acc;
  }
  __syncthreads();

  // ---- per-sample fused encoder matrix per wire: Rx(f3) Rz(f2) Ry(f1) Rx(f0)
  if (lane < 10) {
    const int i = lane;
    const int f = 4*i;
    float a0 = 0.5f * fmaf(xqs[wv][f+0], bnA[f+0], bnC[f+0]);
    float a1 = 0.5f * fmaf(xqs[wv][f+1], bnA[f+1], bnC[f+1]);
    float a2 = 0.5f * fmaf(xqs[wv][f+2], bnA[f+2], bnC[f+2]);
    float a3 = 0.5f * fmaf(xqs[wv][f+3], bnA[f+3], bnC[f+3]);
    float c0 = __cosf(a0), s0 = __sinf(a0);
    float c1 = __cosf(a1), s1 = __sinf(a1);
    float c2 = __cosf(a2), s2 = __sinf(a2);
    float c3 = __cosf(a3), s3 = __sinf(a3);
    float A00r=c1*c0, A00i= s1*s0;
    float A01r=-s1*c0, A01i=-c1*s0;
    float A10r= s1*c0, A10i=-c1*s0;
    float A11r= c1*c0, A11i=-s1*s0;
    float B00r = A00r*c2 + A00i*s2, B00i = A00i*c2 - A00r*s2;
    float B01r = A01r*c2 + A01i*s2, B01i = A01i*c2 - A01r*s2;
    float B10r = A10r*c2 - A10i*s2, B10i = A10i*c2 + A10r*s2;
    float B11r = A11r*c2 - A11i*s2, B11i = A11i*c2 + A11r*s2;
    float* e = &Ebuf[wv][i][0];
    e[0] = c3*B00r + s3*B10i;  e[1] = c3*B00i - s3*B10r;
    e[2] = c3*B01r + s3*B11i;  e[3] = c3*B01i - s3*B11r;
    e[4] = c3*B10r + s3*B00i;  e[5] = c3*B10i - s3*B00r;
    e[6] = c3*B11r + s3*B01i;  e[7] = c3*B11i - s3*B01r;
  }

  // ---- fused F_k = U_{k+1} * E (same wave reads its own Ebuf rows)
  if (lane < 30) {
    const int k = lane/10, i = lane - k*10;
    const float* U = &Gbuf[(k+1)*10 + i][0];
    const float* E = &Ebuf[wv][i][0];
    float u00r=U[0],u00i=U[1],u01r=U[2],u01i=U[3],u10r=U[4],u10i=U[5],u11r=U[6],u11i=U[7];
    float e00r=E[0],e00i=E[1],e01r=E[2],e01i=E[3],e10r=E[4],e10i=E[5],e11r=E[6],e11i=E[7];
    float* F = &Fbuf[wv][k][i][0];
    F[0] = u00r*e00r - u00i*e00i + u01r*e10r - u01i*e10i;
    F[1] = u00r*e00i + u00i*e00r + u01r*e10i + u01i*e10r;
    F[2] = u00r*e01r - u00i*e01i + u01r*e11r - u01i*e11i;
    F[3] = u00r*e01i + u00i*e01r + u01r*e11i + u01i*e11r;
    F[4] = u10r*e00r - u10i*e00i + u11r*e10r - u11i*e10i;
    F[5] = u10r*e00i + u10i*e00r + u11r*e10i + u11i*e10r;
    F[6] = u10r*e01r - u10i*e01i + u11r*e11r - u11i*e11i;
    F[7] = u10r*e01i + u10i*e01r + u11r*e11i + u11i*e11r;
  }

  const bool h0 = (lane & 32) != 0;
  const bool h1 = (lane & 16) != 0;
  const bool h2 = (lane &  8) != 0;
  const bool h3 = (lane &  4) != 0;
  const bool h4 = (lane &  2) != 0;
  const bool h5 = (lane &  1) != 0;
  const int addrg = (lane ^ (lane >> 1)) << 2;
  const int a32   = (lane ^ 32) << 2;

  // ---- init: state = ring( U0 |0..0> ) — ring #1 fused analytically.
  //  amp(L,j) = c(L0) * phi6[b3']phi7[b2'] * phi8[b1']phi9[b0'], where
  //  L0 = gray(L) ^ 48*(j&1);  j' bits: b3'=b3^(L&1), b2'=b2^b3, b1'=b1^b2,
  //  b0'=b0^b1.  (verified vs sequential-CNOT gather; see header)
  //  Folded form (R11-verified): ce/co * p67 recomputed per p.
  v2f R[8], I[8];
  {
    const int l0=lane&1, l1=(lane>>1)&1, l2=(lane>>2)&1,
              l3=(lane>>3)&1, l4=(lane>>4)&1, l5=(lane>>5)&1;
    // cs = phi2[l3^l4] phi3[l2^l3] phi4[l1^l2] phi5[l0^l1]
    float csr, csi;
    {
      int b = l3^l4; csr = Gbuf[2][4*b]; csi = Gbuf[2][4*b+1];
      b = l2^l3; float gr=Gbuf[3][4*b], gi=Gbuf[3][4*b+1];
      float tr = csr*gr - csi*gi, ti = csr*gi + csi*gr; csr=tr; csi=ti;
      b = l1^l2; gr=Gbuf[4][4*b]; gi=Gbuf[4][4*b+1];
      tr = csr*gr - csi*gi; ti = csr*gi + csi*gr; csr=tr; csi=ti;
      b = l0^l1; gr=Gbuf[5][4*b]; gi=Gbuf[5][4*b+1];
      tr = csr*gr - csi*gi; ti = csr*gi + csi*gr; csr=tr; csi=ti;
    }
    // ce = phi0[l5] phi1[l4^l5] cs ; co = phi0[1^l5] phi1[1^(l4^l5)] cs
    float cer,cei,cor_,coi;
    {
      const int b5 = l5, b4 = l4^l5;
      float ar = Gbuf[0][4*b5],     ai = Gbuf[0][4*b5+1];
      float br = Gbuf[1][4*b4],     bi = Gbuf[1][4*b4+1];
      float tr = ar*br - ai*bi,     ti = ar*bi + ai*br;
      cer = tr*csr - ti*csi;  cei = tr*csi + ti*csr;
      ar = Gbuf[0][4*(1^b5)]; ai = Gbuf[0][4*(1^b5)+1];
      br = Gbuf[1][4*(1^b4)]; bi = Gbuf[1][4*(1^b4)+1];
      tr = ar*br - ai*bi;     ti = ar*bi + ai*br;
      cor_ = tr*csr - ti*csi; coi = tr*csi + ti*csr;
    }
    // local pair products
    float p67r[4], p67i[4], p89r[4], p89i[4];
#pragma unroll
    for (int b6=0;b6<2;++b6)
#pragma unroll
      for (int b7=0;b7<2;++b7) {
        const float x6r = Gbuf[6][4*b6], x6i = Gbuf[6][4*b6+1];
        const float x7r = Gbuf[7][4*b7], x7i = Gbuf[7][4*b7+1];
        p67r[b6*2+b7] = x6r*x7r - x6i*x7i;
        p67i[b6*2+b7] = x6r*x7i + x6i*x7r;
      }
#pragma unroll
    for (int b8=0;b8<2;++b8)
#pragma unroll
      for (int b9=0;b9<2;++b9) {
        const float x8r = Gbuf[8][4*b8], x8i = Gbuf[8][4*b8+1];
        const float x9r = Gbuf[9][4*b9], x9i = Gbuf[9][4*b9+1];
        p89r[b8*2+b9] = x8r*x9r - x8i*x9i;
        p89i[b8*2+b9] = x8r*x9i + x8i*x9r;
      }
    // folded: t = (ce|co)*p67 recomputed per p (4 transients vs 16-reg arrays)
#pragma unroll
    for (int p=0;p<8;++p) {
      const int b3 = (p>>2)&1, b2 = (p>>1)&1, b1 = p&1;
      const int i67 = ((b3 ^ l0) << 1) | (b2 ^ b3);
      const int b1p = b1 ^ b2;
      const int ix  = (b1p<<1) | b1;
      const int iy  = (b1p<<1) | (1^b1);
      const float ter  = cer*p67r[i67] - cei*p67i[i67];
      const float tei  = cer*p67i[i67] + cei*p67r[i67];
      const float tor_ = cor_*p67r[i67] - coi*p67i[i67];
      const float toi  = cor_*p67i[i67] + coi*p67r[i67];
      R[p].x = ter*p89r[ix] - tei*p89i[ix];
      I[p].x = ter*p89i[ix] + tei*p89r[ix];
      R[p].y = tor_*p89r[iy] - toi*p89i[iy];
      I[p].y = tor_*p89i[iy] + toi*p89r[iy];
    }
  }

  // ---- main circuit: 3 fused layers with 3 remaining rings
  { const float* F = &Fbuf[wv][0][0][0]; GEN10(F) }
  cnot_ring(R,I,addrg,lane,h5);
  { const float* F = &Fbuf[wv][1][0][0]; GEN10(F) }
  cnot_ring(R,I,addrg,lane,h5);
  { const float* F = &Fbuf[wv][2][0][0]; GEN10(F) }
  cnot_ring(R,I,addrg,lane,h5);

  float* dst = &x1s[wv][0];

  // ---- outs[0]: <Z_w> from probabilities (streamed — no pv[8] array)
  {
    v2f T8 = vs(0.f);
    v2f aa[4];
#pragma unroll
    for (int m=0;m<4;++m) aa[m] = vs(0.f);
#pragma unroll
    for (int p=0;p<8;++p) {
      v2f t = R[p]*R[p] + I[p]*I[p];
      T8 = (p&1) ? (T8 - t) : (T8 + t);
      aa[p>>1] += t;
    }
    v2f T7 = (aa[0]-aa[1]) + (aa[2]-aa[3]);
    v2f T6 = (aa[0]+aa[1]) - (aa[2]+aa[3]);
    v2f S  = (aa[0]+aa[1]) + (aa[2]+aa[3]);
    float q8 = T8.x + T8.y;
    float q7 = T7.x + T7.y;
    float q6 = T6.x + T6.y;
    float q9 = S.x - S.y;
    float P  = S.x + S.y;

    float v = P;
    { float pt = xor1f (v,0);    v = h5 ? (pt - v) : (pt + v); }
    { float pt = xor2f (v,0);    v = h4 ? (pt - v) : (pt + v); }
    { float pt = xor4f (v,0);    v = h3 ? (pt - v) : (pt + v); }
    { float pt = xor8f (v,0);    v = h2 ? (pt - v) : (pt + v); }
    { float pt = xor16p(v,lane); v = h1 ? (pt - v) : (pt + v); }
    { float pt = xor32p(v,lane); v = h0 ? (pt - v) : (pt + v); }

    q6 = dsum(q6); q7 = dsum(q7); q8 = dsum(q8); q9 = dsum(q9);

    if (lane==32) dst[0]=v;
    if (lane==16) dst[1]=v;
    if (lane== 8) dst[2]=v;
    if (lane== 4) dst[3]=v;
    if (lane== 2) dst[4]=v;
    if (lane== 1) dst[5]=v;
    if (lane==63){ dst[6]=q6; dst[7]=q7; dst[8]=q8; dst[9]=q9; }
  }

  // ---- outs[1]=<X>, outs[2]=outs[3]=-<Y>, direct from psi0
  //      (chunked 2x4 pairs, same in-flight cap as gates)
#define XYC(PFN,AUX,HW,W) { \
    v2f U=vs(0.f), V=vs(0.f); \
    _Pragma("unroll") \
    for (int c=0;c<2;++c){ \
      _Pragma("unroll") \
      for (int p=c*4;p<c*4+4;++p) { \
        v2f PR = PFN(R[p],AUX); \
        v2f PI = PFN(I[p],AUX); \
        U += R[p]*PR + I[p]*PI; \
        V += I[p]*PR - R[p]*PI; \
      } \
      if (c==0) __builtin_amdgcn_sched_barrier(0); \
    } \
    float u = U.x + U.y; \
    float vv = V.x + V.y; \
    vv = (HW) ? vv : -vv; \
    u = dsum(u); vv = dsum(vv); \
    if (lane==63){ dst[10+(W)]=u; dst[20+(W)]=vv; dst[30+(W)]=vv; } \
  }
  XYC(xor32pv,lane,h0,0) XYC(xor16pv,lane,h1,1) XYC(xor8v,0,h2,2)
  XYC(xor4v ,0,h3,3) XYC(xor2v ,0,h4,4) XYC(xor1v,0,h5,5)
#undef XYC

#define XYL(PM,W) { \
    v2f U=vs(0.f), V=vs(0.f); \
    _Pragma("unroll") \
    for (int p=0;p<8;++p) if (!(p&(PM))) { \
      const int q=p|(PM); \
      U += R[p]*R[q] + I[p]*I[q]; \
      V += I[p]*R[q] - R[p]*I[q]; \
    } \
    float u = U.x + U.y; \
    float vv = V.x + V.y; \
    u = dsum(u); vv = dsum(vv); \
    if (lane==63){ dst[10+(W)]=2.f*u; float y=-2.f*vv; dst[20+(W)]=y; dst[30+(W)]=y; } \
  }
  XYL(4,6) XYL(2,7) XYL(1,8)
#undef XYL

  {
    float u=0.f, vv=0.f;
#pragma unroll
    for (int p=0;p<8;++p) {
      u  = fmaf(R[p].x, R[p].y, u);  u  = fmaf(I[p].x, I[p].y, u);
      vv = fmaf(I[p].x, R[p].y, vv); vv = fmaf(-R[p].x, I[p].y, vv);
    }
    u = dsum(u); vv = dsum(vv);
    if (lane==63){ dst[19]=2.f*u; float y=-2.f*vv; dst[29]=y; dst[39]=y; }
  }

  // ---- fused epilogue: x2 = relu(x@clin^T+b); out = [x1,x2]@lin^T + b
  __syncthreads();
  if (tix < 160) {
    const int sl = tix/40, f = tix - sl*40;
    const float4* cw = (const float4*)(clin_w + f*40);
    float acc = clin_b[f];
#pragma unroll
    for (int q = 0; q < 10; ++q) {
      float4 v = cw[q];
      acc = fmaf(v.x, xs[sl][4*q+0], acc);
      acc = fmaf(v.y, xs[sl][4*q+1], acc);
      acc = fmaf(v.z, xs[sl][4*q+2], acc);
      acc = fmaf(v.w, xs[sl][4*q+3], acc);
    }
    x2s[sl][f] = fmaxf(acc, 0.f);
  }
  __syncthreads();
  if (tix < 160) {
    const int sl = tix/40, f = tix - sl*40;
    const float4* lw = (const float4*)(lin_w + f*80);
    float o = lin_b[f];
#pragma unroll
    for (int q = 0; q < 10; ++q) {
      float4 v = lw[q];
      o = fmaf(v.x, x1s[sl][4*q+0], o);
      o = fmaf(v.y, x1s[sl][4*q+1], o);
      o = fmaf(v.z, x1s[sl][4*q+2], o);
      o = fmaf(v.w, x1s[sl][4*q+3], o);
    }
#pragma unroll
    for (int q = 10; q < 20; ++q) {
      float4 v = lw[q];
      o = fmaf(v.x, x2s[sl][4*(q-10)+0], o);
      o = fmaf(v.y, x2s[sl][4*(q-10)+1], o);
      o = fmaf(v.z, x2s[sl][4*(q-10)+2], o);
      o = fmaf(v.w, x2s[sl][4*(q-10)+3], o);
    }
    out[blockIdx.x*160 + tix] = o;
  }
}

// ---------------- launch ---------------------------------------------------
extern "C" void kernel_launch(void* const* d_in, const int* in_sizes, int n_in,
                              void* d_out, int out_size, void* d_ws, size_t ws_size,
                              hipStream_t stream)
{
  const float* x      = (const float*)d_in[0];
  const float* qlin_w = (const float*)d_in[1];
  const float* qlin_b = (const float*)d_in[2];
  const float* bn_g   = (const float*)d_in[3];
  const float* bn_b   = (const float*)d_in[4];
  const float* clin_w = (const float*)d_in[5];
  const float* clin_b = (const float*)d_in[6];
  const float* lin_w  = (const float*)d_in[7];
  const float* lin_b  = (const float*)d_in[8];
  const float* rz1    = (const float*)d_in[9];
  const float* ry1    = (const float*)d_in[10];
  const float* rz2    = (const float*)d_in[11];

  float* ps  = (float*)d_ws;     // 640 floats of partials
  float* out = (float*)d_out;

  hipLaunchKernelGGL(k_pre, dim3(320),  dim3(256), 0, stream, x, qlin_w, qlin_b, ps);
  hipLaunchKernelGGL(k_qnn, dim3(2048), dim3(256), 0, stream,
                     x, qlin_w, qlin_b, ps, bn_g, bn_b, rz1, ry1, rz2,
                     clin_w, clin_b, lin_w, lin_b, out);
}